// Round 4
// baseline (693.041 us; speedup 1.0000x reference)
//
#include <hip/hip_runtime.h>

#define BATCH 128

// ---------------------------------------------------------------------------
// Spline activation: act[0] = silu(x), act[1..8] = cubic B-spline bases
// Grid: g[i] = (i-3)*0.4 - 1.0 (uniform; all denominators constant-fold)
// ---------------------------------------------------------------------------
__device__ __forceinline__ void spline_acts(float xv, float act[9]) {
    act[0] = xv * (1.0f / (1.0f + __expf(-xv)));  // silu
    float g[12];
#pragma unroll
    for (int i = 0; i < 12; ++i) g[i] = (float)(i - 3) * 0.4f - 1.0f;
    float bb[11];
#pragma unroll
    for (int c = 0; c < 11; ++c) bb[c] = (xv >= g[c] && xv < g[c + 1]) ? 1.0f : 0.0f;
#pragma unroll
    for (int k = 1; k <= 3; ++k) {
#pragma unroll
        for (int c = 0; c + k < 11; ++c) {
            float left  = (xv - g[c]) * (1.0f / (g[c + k] - g[c])) * bb[c];
            float right = (g[c + k + 1] - xv) * (1.0f / (g[c + k + 1] - g[c + 1])) * bb[c + 1];
            bb[c] = left + right;
        }
    }
#pragma unroll
    for (int c = 0; c < 8; ++c) act[c + 1] = bb[c];
}

// ---------------------------------------------------------------------------
// Pack weights: wpack[(cin*9+tap)*9*O + j*O + o] = j==0 ? bw : sw*sc
// ---------------------------------------------------------------------------
__device__ __forceinline__ void pack_one(int i, const float* bw, const float* sw,
                                         const float* sc, float* out, int F, int O) {
    int o = i % O;
    int j = (i / O) % 9;
    int f = i / (9 * O);
    float v;
    if (j == 0) v = bw[o * F + f];
    else        v = sw[(o * F + f) * 8 + (j - 1)] * sc[o * F + f];
    out[i] = v;
}

__global__ void pack_all(const float* __restrict__ bw1, const float* __restrict__ sw1,
                         const float* __restrict__ sc1, const float* __restrict__ bw2,
                         const float* __restrict__ sw2, const float* __restrict__ sc2,
                         const float* __restrict__ bw3, const float* __restrict__ sw3,
                         const float* __restrict__ sc3, const float* __restrict__ bw4,
                         const float* __restrict__ sw4, const float* __restrict__ sc4,
                         float* __restrict__ ws) {
    int i = blockIdx.x * blockDim.x + threadIdx.x;
    if (i < 972)        pack_one(i,         bw1, sw1, sc1, ws,         27, 4);
    else if (i < 3564)  pack_one(i - 972,   bw2, sw2, sc2, ws + 972,   36, 8);
    else if (i < 13932) pack_one(i - 3564,  bw3, sw3, sc3, ws + 3564,  72, 16);
    else if (i < 55404) pack_one(i - 13932, bw4, sw4, sc4, ws + 13932, 144, 32);
}

// ---------------------------------------------------------------------------
// Interleaved spline store helper: 9 acts + 1 pad, stride 10, float2 stores.
// ---------------------------------------------------------------------------
__device__ __forceinline__ void store_sp10(float* ob, const float a9[9]) {
    *(float2*)(ob + 0) = make_float2(a9[0], a9[1]);
    *(float2*)(ob + 2) = make_float2(a9[2], a9[3]);
    *(float2*)(ob + 4) = make_float2(a9[4], a9[5]);
    *(float2*)(ob + 6) = make_float2(a9[6], a9[7]);
    *(float2*)(ob + 8) = make_float2(a9[8], 0.0f);
}

// ---------------------------------------------------------------------------
// conv1: reads raw x (B,3,H,W), inline splines, writes SP2 interleaved-10.
// ---------------------------------------------------------------------------
template <int H, int W>
__global__ __launch_bounds__(256) void conv1_kernel(const float* __restrict__ x,
                                                    const float* __restrict__ wp,
                                                    float* __restrict__ SPout) {
    constexpr int HW = H * W, CIN = 3, COUT = 4;
    int n = blockIdx.x * 256 + threadIdx.x;
    int w = n % W, h = (n / W) % H, b = n / HW;
    float acc[COUT] = {};
    const float* xb = x + (size_t)b * CIN * HW;
#pragma unroll 1
    for (int cin = 0; cin < CIN; ++cin) {
        const float* xc = xb + cin * HW;
#pragma unroll
        for (int dh = 0; dh < 3; ++dh) {
            int hh = h + dh - 1;
#pragma unroll
            for (int dw = 0; dw < 3; ++dw) {
                int ww = w + dw - 1;
                bool inb = ((unsigned)hh < (unsigned)H) && ((unsigned)ww < (unsigned)W);
                float xv = inb ? xc[hh * W + ww] : 0.0f;  // zero-pad -> spline(0)
                float a9[9];
                spline_acts(xv, a9);
                const float* wrow = wp + (size_t)(cin * 9 + dh * 3 + dw) * 9 * COUT;
#pragma unroll
                for (int j = 0; j < 9; ++j)
#pragma unroll
                    for (int co = 0; co < COUT; ++co)
                        acc[co] = fmaf(a9[j], wrow[j * COUT + co], acc[co]);
            }
        }
    }
    int p = h * W + w;
#pragma unroll
    for (int co = 0; co < COUT; ++co) {
        float a9[9];
        spline_acts(acc[co], a9);
        store_sp10(SPout + ((size_t)(b * COUT + co) * HW + p) * 10, a9);
    }
}

// ---------------------------------------------------------------------------
// KAN conv over interleaved-10 splines. SP: (B,CIN,HW,10).
// blockIdx.y = cout group of CO. EPI=1 -> spline-expand epilogue (next SP).
// ---------------------------------------------------------------------------
template <int CIN, int COUT, int CO, int H, int W, int EPI>
__global__ __launch_bounds__(256) void conv_i10(const float* __restrict__ SP,
                                                const float* __restrict__ wp,
                                                float* __restrict__ out) {
    constexpr int HW = H * W;
    int n = blockIdx.x * 256 + threadIdx.x;
    const int o0 = blockIdx.y * CO;
    int w = n % W, h = (n / W) % H, b = n / HW;

    const float ZP3 = 0.02083333333f, ZP4 = 0.47916666667f;  // spline(0) nonzeros

    float acc[CO] = {};
    const float* spb = SP + (size_t)b * CIN * HW * 10;
#pragma unroll 1
    for (int cin = 0; cin < CIN; ++cin) {
        const float* spc = spb + (size_t)cin * HW * 10;
#pragma unroll
        for (int dh = 0; dh < 3; ++dh) {
            int hh = h + dh - 1;
#pragma unroll
            for (int dw = 0; dw < 3; ++dw) {
                int ww = w + dw - 1;
                bool inb = ((unsigned)hh < (unsigned)H) && ((unsigned)ww < (unsigned)W);
                int off = inb ? (hh * W + ww) * 10 : 0;
                float2 v0 = inb ? *(const float2*)(spc + off + 0) : make_float2(0.f, 0.f);
                float2 v1 = inb ? *(const float2*)(spc + off + 2) : make_float2(0.f, ZP3);
                float2 v2 = inb ? *(const float2*)(spc + off + 4) : make_float2(ZP4, ZP4);
                float2 v3 = inb ? *(const float2*)(spc + off + 6) : make_float2(ZP3, 0.f);
                float  v8 = inb ? spc[off + 8] : 0.f;
                const float* wrow = wp + (size_t)(cin * 9 + dh * 3 + dw) * 9 * COUT + o0;
#pragma unroll
                for (int co = 0; co < CO; ++co) {
                    float a = acc[co];
                    a = fmaf(v0.x, wrow[0 * COUT + co], a);
                    a = fmaf(v0.y, wrow[1 * COUT + co], a);
                    a = fmaf(v1.x, wrow[2 * COUT + co], a);
                    a = fmaf(v1.y, wrow[3 * COUT + co], a);
                    a = fmaf(v2.x, wrow[4 * COUT + co], a);
                    a = fmaf(v2.y, wrow[5 * COUT + co], a);
                    a = fmaf(v3.x, wrow[6 * COUT + co], a);
                    a = fmaf(v3.y, wrow[7 * COUT + co], a);
                    a = fmaf(v8,   wrow[8 * COUT + co], a);
                    acc[co] = a;
                }
            }
        }
    }

    int p = h * W + w;
    if (EPI == 0) {
        float* ob = out + ((size_t)b * COUT + o0) * HW + p;
#pragma unroll
        for (int co = 0; co < CO; ++co) ob[(size_t)co * HW] = acc[co];
    } else {
#pragma unroll
        for (int co = 0; co < CO; ++co) {
            float a9[9];
            spline_acts(acc[co], a9);
            store_sp10(out + ((size_t)(b * COUT + o0 + co) * HW + p) * 10, a9);
        }
    }
}

// ---------------------------------------------------------------------------
// Pool (2x2 max) + spline expansion -> interleaved-10.
// in: (BC, H, W) -> SP: (BC, H/2*W/2, 10)
// ---------------------------------------------------------------------------
__global__ void pool_spline_i10(const float* __restrict__ in, float* __restrict__ SP,
                                int H, int W, int total) {
    int i = blockIdx.x * blockDim.x + threadIdx.x;
    if (i >= total) return;
    int W2 = W / 2, H2 = H / 2, HW2 = W2 * H2;
    int w = i % W2;
    int h = (i / W2) % H2;
    int bc = i / HW2;
    const float* p = in + ((size_t)bc * H + 2 * h) * W + 2 * w;
    float m = fmaxf(fmaxf(p[0], p[1]), fmaxf(p[W], p[W + 1]));
    float a9[9];
    spline_acts(m, a9);
    store_sp10(SP + ((size_t)bc * HW2 + h * W2 + w) * 10, a9);
}

// ---------------------------------------------------------------------------
// Plain 2x2 max pool: in (BC, H, W) -> out (BC, H/2, W/2)
// ---------------------------------------------------------------------------
__global__ void maxpool_kernel(const float* __restrict__ in, float* __restrict__ out,
                               int H, int W, int total) {
    int i = blockIdx.x * blockDim.x + threadIdx.x;
    if (i >= total) return;
    int W2 = W / 2, H2 = H / 2, HW2 = W2 * H2;
    int w = i % W2;
    int h = (i / W2) % H2;
    int bc = i / HW2;
    const float* p = in + ((size_t)bc * H + 2 * h) * W + 2 * w;
    out[i] = fmaxf(fmaxf(p[0], p[1]), fmaxf(p[W], p[W + 1]));
}

// ---------------------------------------------------------------------------
// fc_big: 64x64 tile, 4x4/thread, K_TILE=32, split-K via blockIdx.z.
// ---------------------------------------------------------------------------
template <int SPLIT>
__global__ __launch_bounds__(256) void fc_big(const float* __restrict__ A,
                                              const float* __restrict__ Wt,
                                              float* __restrict__ part,
                                              int M, int N, int K) {
    __shared__ float As[32][68];
    __shared__ float Ws[32][68];
    const int tid = threadIdx.x;
    const int tx = tid & 15, ty = tid >> 4;
    const int bm = blockIdx.y * 64, bn = blockIdx.x * 64;
    const int kc = K / SPLIT;
    const int kbeg = blockIdx.z * kc;
    float acc[4][4] = {};
    for (int k0 = kbeg; k0 < kbeg + kc; k0 += 32) {
#pragma unroll
        for (int e = 0; e < 8; ++e) {
            int g = e * 256 + tid;
            int k = g & 31, r = g >> 5;
            As[k][r] = A[(size_t)(bm + r) * K + k0 + k];
            Ws[k][r] = Wt[(size_t)(bn + r) * K + k0 + k];
        }
        __syncthreads();
#pragma unroll
        for (int kk = 0; kk < 32; ++kk) {
            float4 av = *(const float4*)(&As[kk][ty * 4]);
            float4 wv = *(const float4*)(&Ws[kk][tx * 4]);
            acc[0][0] = fmaf(av.x, wv.x, acc[0][0]);
            acc[0][1] = fmaf(av.x, wv.y, acc[0][1]);
            acc[0][2] = fmaf(av.x, wv.z, acc[0][2]);
            acc[0][3] = fmaf(av.x, wv.w, acc[0][3]);
            acc[1][0] = fmaf(av.y, wv.x, acc[1][0]);
            acc[1][1] = fmaf(av.y, wv.y, acc[1][1]);
            acc[1][2] = fmaf(av.y, wv.z, acc[1][2]);
            acc[1][3] = fmaf(av.y, wv.w, acc[1][3]);
            acc[2][0] = fmaf(av.z, wv.x, acc[2][0]);
            acc[2][1] = fmaf(av.z, wv.y, acc[2][1]);
            acc[2][2] = fmaf(av.z, wv.z, acc[2][2]);
            acc[2][3] = fmaf(av.z, wv.w, acc[2][3]);
            acc[3][0] = fmaf(av.w, wv.x, acc[3][0]);
            acc[3][1] = fmaf(av.w, wv.y, acc[3][1]);
            acc[3][2] = fmaf(av.w, wv.z, acc[3][2]);
            acc[3][3] = fmaf(av.w, wv.w, acc[3][3]);
        }
        __syncthreads();
    }
    float* p = part + (size_t)blockIdx.z * M * N;
#pragma unroll
    for (int i = 0; i < 4; ++i) {
        float4 v = make_float4(acc[i][0], acc[i][1], acc[i][2], acc[i][3]);
        *(float4*)&p[(size_t)(bm + ty * 4 + i) * N + (bn + tx * 4)] = v;
    }
}

template <int SPLIT>
__global__ void fc_reduce(const float* __restrict__ part, const float* __restrict__ bias,
                          float* __restrict__ C, int MN, int N, int relu) {
    int i = blockIdx.x * 256 + threadIdx.x;
    if (i >= MN) return;
    float s = bias[i % N];
#pragma unroll
    for (int z = 0; z < SPLIT; ++z) s += part[(size_t)z * MN + i];
    C[i] = relu ? fmaxf(s, 0.f) : s;
}

// ---------------------------------------------------------------------------
// fc3: M=128, N=10, K=1024. One wave per output element.
// ---------------------------------------------------------------------------
__global__ __launch_bounds__(256) void fc3_kernel(const float* __restrict__ A,
                                                  const float* __restrict__ Wt,
                                                  const float* __restrict__ bias,
                                                  float* __restrict__ C) {
    int gid = blockIdx.x * 256 + threadIdx.x;
    int wid = gid >> 6;
    int lane = gid & 63;
    int m = wid / 10, n = wid - m * 10;
    const float4* a = (const float4*)(A + (size_t)m * 1024);
    const float4* w = (const float4*)(Wt + (size_t)n * 1024);
    float s = 0.f;
#pragma unroll
    for (int it = 0; it < 4; ++it) {
        float4 av = a[it * 64 + lane];
        float4 wv = w[it * 64 + lane];
        s += av.x * wv.x + av.y * wv.y + av.z * wv.z + av.w * wv.w;
    }
#pragma unroll
    for (int off = 32; off; off >>= 1) s += __shfl_xor(s, off);
    if (lane == 0) C[wid] = s + bias[n];
}

// ---------------------------------------------------------------------------
extern "C" void kernel_launch(void* const* d_in, const int* in_sizes, int n_in,
                              void* d_out, int out_size, void* d_ws, size_t ws_size,
                              hipStream_t stream) {
    const float* x   = (const float*)d_in[0];
    const float* bw1 = (const float*)d_in[1];
    const float* sw1 = (const float*)d_in[2];
    const float* sc1 = (const float*)d_in[3];
    const float* bw2 = (const float*)d_in[4];
    const float* sw2 = (const float*)d_in[5];
    const float* sc2 = (const float*)d_in[6];
    const float* bw3 = (const float*)d_in[7];
    const float* sw3 = (const float*)d_in[8];
    const float* sc3 = (const float*)d_in[9];
    const float* bw4 = (const float*)d_in[10];
    const float* sw4 = (const float*)d_in[11];
    const float* sc4 = (const float*)d_in[12];
    const float* w1  = (const float*)d_in[13];
    const float* b1  = (const float*)d_in[14];
    const float* w2  = (const float*)d_in[15];
    const float* b2  = (const float*)d_in[16];
    const float* w3  = (const float*)d_in[17];
    const float* b3  = (const float*)d_in[18];

    float* ws  = (float*)d_ws;
    float* wp1 = ws;           // [0,972)
    float* wp2 = ws + 972;     // [972,3564)
    float* wp3 = ws + 3564;    // [3564,13932)
    float* wp4 = ws + 13932;   // [13932,55404)
    float* base = ws + 65536;
    // liveness-packed activation buffers (floats from base):
    float* SP2    = base;              // [0, 5242880)        (B,4,1024,10)
    float* out2   = base + 5242880;    // [5242880, 6291456)  (B,8,32,32)
    float* SP3    = base;              // [0, 2621440)        (B,8,256,10)  over dead SP2
    float* SP4    = base + 2621440;    // [2621440, 7864320)  (B,16,256,10)
    float* out4   = base;              // [0, 1048576)        (B,32,16,16)  over dead SP3
    float* pooled = base + 1048576;    // [1048576, 1310720)  (B,2048)
    float* part1  = base + 1310720;    // [1310720, 3407872)  8x(128,2048)
    float* fc1o   = base + 3407872;    // [3407872, 3670016)
    float* part2  = base + 3670016;    // [3670016, 4718592)  8x(128,1024)
    float* fc2o   = base + 4718592;    // [4718592, 4849664)
    // peak = (65536 + 7864320) * 4B = 31.7 MB

    pack_all<<<(55404 + 255) / 256, 256, 0, stream>>>(bw1, sw1, sc1, bw2, sw2, sc2,
                                                      bw3, sw3, sc3, bw4, sw4, sc4, ws);

    // conv1: x -> SP2 (inline input splines + spline epilogue)
    conv1_kernel<32, 32><<<512, 256, 0, stream>>>(x, wp1, SP2);
    // conv2: SP2 -> out2 raw; 2 cout groups of 4 (16 waves/CU)
    conv_i10<4, 8, 4, 32, 32, 0><<<dim3(512, 2), 256, 0, stream>>>(SP2, wp2, out2);
    // pool1 + spline: out2 (1024 imgs 32x32) -> SP3
    pool_spline_i10<<<1024, 256, 0, stream>>>(out2, SP3, 32, 32, 262144);
    // conv3: SP3 -> SP4 (spline epilogue); 8 groups of 2 (16 waves/CU)
    conv_i10<8, 16, 2, 16, 16, 1><<<dim3(128, 8), 256, 0, stream>>>(SP3, wp3, SP4);
    // conv4: SP4 -> out4 raw; 8 groups of 4 (16 waves/CU)
    conv_i10<16, 32, 4, 16, 16, 0><<<dim3(128, 8), 256, 0, stream>>>(SP4, wp4, out4);
    // pool2: out4 -> pooled (B,2048)
    maxpool_kernel<<<1024, 256, 0, stream>>>(out4, pooled, 16, 16, 262144);
    // fc1: relu(pooled @ w1.T + b1), split-K=8
    fc_big<8><<<dim3(32, 2, 8), 256, 0, stream>>>(pooled, w1, part1, 128, 2048, 2048);
    fc_reduce<8><<<1024, 256, 0, stream>>>(part1, b1, fc1o, 262144, 2048, 1);
    // fc2: relu(fc1o @ w2.T + b2), split-K=8
    fc_big<8><<<dim3(16, 2, 8), 256, 0, stream>>>(fc1o, w2, part2, 128, 1024, 2048);
    fc_reduce<8><<<512, 256, 0, stream>>>(part2, b2, fc2o, 131072, 1024, 1);
    // fc3
    fc3_kernel<<<320, 256, 0, stream>>>(fc2o, w3, b3, (float*)d_out);
}

// Round 5
// 606.084 us; speedup vs baseline: 1.1435x; 1.1435x over previous
//
#include <hip/hip_runtime.h>

#define BATCH 128

// ---------------------------------------------------------------------------
// Spline activation: act[0] = silu(x), act[1..8] = cubic B-spline bases
// Grid: g[i] = (i-3)*0.4 - 1.0 (uniform; all denominators constant-fold)
// ---------------------------------------------------------------------------
__device__ __forceinline__ void spline_acts(float xv, float act[9]) {
    act[0] = xv * (1.0f / (1.0f + __expf(-xv)));  // silu
    float g[12];
#pragma unroll
    for (int i = 0; i < 12; ++i) g[i] = (float)(i - 3) * 0.4f - 1.0f;
    float bb[11];
#pragma unroll
    for (int c = 0; c < 11; ++c) bb[c] = (xv >= g[c] && xv < g[c + 1]) ? 1.0f : 0.0f;
#pragma unroll
    for (int k = 1; k <= 3; ++k) {
#pragma unroll
        for (int c = 0; c + k < 11; ++c) {
            float left  = (xv - g[c]) * (1.0f / (g[c + k] - g[c])) * bb[c];
            float right = (g[c + k + 1] - xv) * (1.0f / (g[c + k + 1] - g[c + 1])) * bb[c + 1];
            bb[c] = left + right;
        }
    }
#pragma unroll
    for (int c = 0; c < 8; ++c) act[c + 1] = bb[c];
}

// spline_acts(0.0f) — activation vector of a zero-padded tap.
__device__ __constant__ float ZPAD[9] = {0.0f, 0.0f, 0.0f, 0.02083333333f,
                                         0.47916666667f, 0.47916666667f,
                                         0.02083333333f, 0.0f, 0.0f};
// compile-time copy for unrolled selects
__device__ __forceinline__ constexpr float zpc(int j) {
    return (j == 3 || j == 6) ? 0.02083333333f
         : (j == 4 || j == 5) ? 0.47916666667f : 0.0f;
}

// ---------------------------------------------------------------------------
// Pack weights: wpack[(cin*9+tap)*9*O + j*O + o] = j==0 ? bw : sw*sc
// ---------------------------------------------------------------------------
__device__ __forceinline__ void pack_one(int i, const float* bw, const float* sw,
                                         const float* sc, float* out, int F, int O) {
    int o = i % O;
    int j = (i / O) % 9;
    int f = i / (9 * O);
    float v;
    if (j == 0) v = bw[o * F + f];
    else        v = sw[(o * F + f) * 8 + (j - 1)] * sc[o * F + f];
    out[i] = v;
}

__global__ void pack_all(const float* __restrict__ bw1, const float* __restrict__ sw1,
                         const float* __restrict__ sc1, const float* __restrict__ bw2,
                         const float* __restrict__ sw2, const float* __restrict__ sc2,
                         const float* __restrict__ bw3, const float* __restrict__ sw3,
                         const float* __restrict__ sc3, const float* __restrict__ bw4,
                         const float* __restrict__ sw4, const float* __restrict__ sc4,
                         float* __restrict__ ws) {
    int i = blockIdx.x * blockDim.x + threadIdx.x;
    if (i < 972)        pack_one(i,         bw1, sw1, sc1, ws,         27, 4);
    else if (i < 3564)  pack_one(i - 972,   bw2, sw2, sc2, ws + 972,   36, 8);
    else if (i < 13932) pack_one(i - 3564,  bw3, sw3, sc3, ws + 3564,  72, 16);
    else if (i < 55404) pack_one(i - 13932, bw4, sw4, sc4, ws + 13932, 144, 32);
}

// ---------------------------------------------------------------------------
// conv1: raw x (B,3,32,32), inline splines; epilogue spline -> SP2 planar
// SP2: (B, 4, 9, 1024)
// ---------------------------------------------------------------------------
__global__ __launch_bounds__(256) void conv1_kernel(const float* __restrict__ x,
                                                    const float* __restrict__ wp,
                                                    float* __restrict__ SPout) {
    constexpr int H = 32, W = 32, HW = 1024, CIN = 3, COUT = 4;
    int n = blockIdx.x * 256 + threadIdx.x;
    int w = n % W, h = (n / W) % H, b = n / HW;
    float acc[COUT] = {};
    const float* xb = x + (size_t)b * CIN * HW;
#pragma unroll 1
    for (int cin = 0; cin < CIN; ++cin) {
        const float* xc = xb + cin * HW;
#pragma unroll
        for (int dh = 0; dh < 3; ++dh) {
            int hh = h + dh - 1;
#pragma unroll
            for (int dw = 0; dw < 3; ++dw) {
                int ww = w + dw - 1;
                bool inb = ((unsigned)hh < (unsigned)H) && ((unsigned)ww < (unsigned)W);
                float xv = inb ? xc[hh * W + ww] : 0.0f;
                float a9[9];
                spline_acts(xv, a9);
                const float* wrow = wp + (size_t)(cin * 9 + dh * 3 + dw) * 9 * COUT;
#pragma unroll
                for (int j = 0; j < 9; ++j)
#pragma unroll
                    for (int co = 0; co < COUT; ++co)
                        acc[co] = fmaf(a9[j], wrow[j * COUT + co], acc[co]);
            }
        }
    }
    int p = h * W + w;
#pragma unroll
    for (int co = 0; co < COUT; ++co) {
        float a9[9];
        spline_acts(acc[co], a9);
        float* ob = SPout + ((size_t)(b * COUT + co) * 9) * HW + p;
#pragma unroll
        for (int j = 0; j < 9; ++j) ob[j * HW] = a9[j];
    }
}

// ---------------------------------------------------------------------------
// conv2 + maxpool + spline epilogue.
// SP2 (B,4,9,32,32) -> SP3 (B,8,9,16,16). Block = one 8-row strip of one image.
// LDS stages 4cin x 9j x 10rows x 32 = 46KB (halo rows pre-filled with ZPAD).
// ---------------------------------------------------------------------------
__global__ __launch_bounds__(256) void conv2_pool(const float* __restrict__ SP,
                                                  const float* __restrict__ wp,
                                                  float* __restrict__ SPout) {
    constexpr int COUT = 8;
    __shared__ float lds[4 * 9 * 10 * 32];  // 11520 floats
    int bid = blockIdx.x;
    int strip = bid & 3, b = bid >> 2;
    int r0 = strip * 8;
    const float* spb = SP + (size_t)b * 4 * 9 * 1024;
    // stage 2880 float4s
#pragma unroll
    for (int e = 0; e < 12; ++e) {
        int idx = e * 256 + threadIdx.x;
        if (idx < 2880) {
            int seg = idx / 80;   // cin*9 + j
            int off4 = idx % 80;  // 10 rows x 8 float4
            int j = seg % 9;
            int grow = r0 - 1 + (off4 >> 3);
            int col4 = off4 & 7;
            float4 v;
            if ((unsigned)grow < 32u)
                v = *(const float4*)(spb + (size_t)seg * 1024 + grow * 32 + col4 * 4);
            else { float z = ZPAD[j]; v = make_float4(z, z, z, z); }
            *(float4*)(&lds[seg * 320 + off4 * 4]) = v;
        }
    }
    __syncthreads();

    int col = threadIdx.x & 31, lrow = threadIdx.x >> 5;  // 8 rows x 32 cols
    float acc[COUT] = {};
#pragma unroll 1
    for (int cin = 0; cin < 4; ++cin) {
#pragma unroll
        for (int dh = 0; dh < 3; ++dh) {
            int srow = lrow + dh;  // 0..9 in staged rows
#pragma unroll
            for (int dw = 0; dw < 3; ++dw) {
                int ww = col + dw - 1;
                bool inw = (unsigned)ww < 32u;
                int wc = inw ? ww : 0;
                const float* lp = &lds[(cin * 9) * 320 + srow * 32 + wc];
                const float* wrow = wp + (size_t)(cin * 9 + dh * 3 + dw) * 9 * COUT;
                float s[9];
#pragma unroll
                for (int j = 0; j < 9; ++j) s[j] = lp[j * 320];
#pragma unroll
                for (int j = 0; j < 9; ++j) {
                    float sj = inw ? s[j] : zpc(j);
#pragma unroll
                    for (int co = 0; co < COUT; ++co)
                        acc[co] = fmaf(sj, wrow[j * COUT + co], acc[co]);
                }
            }
        }
    }

    // 2x2 maxpool within wave (lanes: 2 rows x 32 cols) + spline epilogue
    bool act = ((col & 1) == 0) && ((lrow & 1) == 0);
    int ph = (r0 + lrow) >> 1, pw = col >> 1;
#pragma unroll
    for (int co = 0; co < COUT; ++co) {
        float v = acc[co];
        v = fmaxf(v, __shfl_xor(v, 1));
        v = fmaxf(v, __shfl_xor(v, 32));
        acc[co] = v;
    }
    if (act) {
        float* ob = SPout + (size_t)b * COUT * 9 * 256;
#pragma unroll
        for (int co = 0; co < COUT; ++co) {
            float a9[9];
            spline_acts(acc[co], a9);
#pragma unroll
            for (int j = 0; j < 9; ++j) ob[(co * 9 + j) * 256 + ph * 16 + pw] = a9[j];
        }
    }
}

// ---------------------------------------------------------------------------
// conv3 + spline epilogue. SP3 (B,8,9,256) -> SP4 (B,16,9,256).
// Block = one 16x16 image, all 8 cins staged in LDS (72KB). CO couts/block.
// ---------------------------------------------------------------------------
template <int CO>
__global__ __launch_bounds__(256) void conv3_kernel(const float* __restrict__ SP,
                                                    const float* __restrict__ wp,
                                                    float* __restrict__ SPout) {
    __shared__ float lds[8 * 9 * 256];  // 18432 floats = 72KB
    int b = blockIdx.x;
    int o0 = blockIdx.y * CO;
    const float* spb = SP + (size_t)b * 18432;
#pragma unroll
    for (int e = 0; e < 18; ++e) {
        int idx = e * 256 + threadIdx.x;
        *(float4*)(&lds[idx * 4]) = *(const float4*)(spb + idx * 4);
    }
    __syncthreads();

    int col = threadIdx.x & 15, lrow = threadIdx.x >> 4;
    float acc[CO] = {};
#pragma unroll 1
    for (int cin = 0; cin < 8; ++cin) {
#pragma unroll
        for (int dh = 0; dh < 3; ++dh) {
            int hh = lrow + dh - 1;
#pragma unroll
            for (int dw = 0; dw < 3; ++dw) {
                int ww = col + dw - 1;
                bool inb = ((unsigned)hh < 16u) && ((unsigned)ww < 16u);
                int li = inb ? hh * 16 + ww : 0;
                const float* lp = &lds[cin * 9 * 256 + li];
                const float* wrow = wp + (size_t)(cin * 9 + dh * 3 + dw) * 9 * 16 + o0;
                float s[9];
#pragma unroll
                for (int j = 0; j < 9; ++j) s[j] = lp[j * 256];
#pragma unroll
                for (int j = 0; j < 9; ++j) {
                    float sj = inb ? s[j] : zpc(j);
#pragma unroll
                    for (int co = 0; co < CO; ++co)
                        acc[co] = fmaf(sj, wrow[j * 16 + co], acc[co]);
                }
            }
        }
    }

    int p = threadIdx.x;
#pragma unroll
    for (int co = 0; co < CO; ++co) {
        float a9[9];
        spline_acts(acc[co], a9);
        float* ob = SPout + ((size_t)(b * 16 + o0 + co) * 9) * 256 + p;
#pragma unroll
        for (int j = 0; j < 9; ++j) ob[j * 256] = a9[j];
    }
}

// ---------------------------------------------------------------------------
// conv4 + maxpool. SP4 (B,16,9,256) -> pooled (B, 32*8*8).
// Block = one image; 16 cins staged in two 8-cin LDS phases (72KB each).
// ---------------------------------------------------------------------------
template <int CO>
__global__ __launch_bounds__(256) void conv4_pool(const float* __restrict__ SP,
                                                  const float* __restrict__ wp,
                                                  float* __restrict__ pooled) {
    __shared__ float lds[8 * 9 * 256];  // 72KB
    int b = blockIdx.x;
    int o0 = blockIdx.y * CO;
    int col = threadIdx.x & 15, lrow = threadIdx.x >> 4;
    const float* spb = SP + (size_t)b * 36864;
    float acc[CO] = {};
#pragma unroll 1
    for (int phase = 0; phase < 2; ++phase) {
        __syncthreads();
#pragma unroll
        for (int e = 0; e < 18; ++e) {
            int idx = e * 256 + threadIdx.x;
            *(float4*)(&lds[idx * 4]) =
                *(const float4*)(spb + phase * 18432 + idx * 4);
        }
        __syncthreads();
#pragma unroll 1
        for (int c8 = 0; c8 < 8; ++c8) {
            int cin = phase * 8 + c8;
#pragma unroll
            for (int dh = 0; dh < 3; ++dh) {
                int hh = lrow + dh - 1;
#pragma unroll
                for (int dw = 0; dw < 3; ++dw) {
                    int ww = col + dw - 1;
                    bool inb = ((unsigned)hh < 16u) && ((unsigned)ww < 16u);
                    int li = inb ? hh * 16 + ww : 0;
                    const float* lp = &lds[c8 * 9 * 256 + li];
                    const float* wrow = wp + (size_t)(cin * 9 + dh * 3 + dw) * 9 * 32 + o0;
                    float s[9];
#pragma unroll
                    for (int j = 0; j < 9; ++j) s[j] = lp[j * 256];
#pragma unroll
                    for (int j = 0; j < 9; ++j) {
                        float sj = inb ? s[j] : zpc(j);
#pragma unroll
                        for (int co = 0; co < CO; ++co)
                            acc[co] = fmaf(sj, wrow[j * 32 + co], acc[co]);
                    }
                }
            }
        }
    }

    // 2x2 maxpool within wave (lanes: 4 rows x 16 cols)
    bool act = ((col & 1) == 0) && ((lrow & 1) == 0);
    int ph = lrow >> 1, pw = col >> 1;
#pragma unroll
    for (int co = 0; co < CO; ++co) {
        float v = acc[co];
        v = fmaxf(v, __shfl_xor(v, 1));
        v = fmaxf(v, __shfl_xor(v, 16));
        if (act) pooled[(size_t)b * 2048 + (o0 + co) * 64 + ph * 8 + pw] = v;
    }
}

// ---------------------------------------------------------------------------
// fc_big: 64x64 tile, 4x4/thread, K_TILE=32, split-K via blockIdx.z.
// ---------------------------------------------------------------------------
template <int SPLIT>
__global__ __launch_bounds__(256) void fc_big(const float* __restrict__ A,
                                              const float* __restrict__ Wt,
                                              float* __restrict__ part,
                                              int M, int N, int K) {
    __shared__ float As[32][68];
    __shared__ float Ws[32][68];
    const int tid = threadIdx.x;
    const int tx = tid & 15, ty = tid >> 4;
    const int bm = blockIdx.y * 64, bn = blockIdx.x * 64;
    const int kc = K / SPLIT;
    const int kbeg = blockIdx.z * kc;
    float acc[4][4] = {};
    for (int k0 = kbeg; k0 < kbeg + kc; k0 += 32) {
#pragma unroll
        for (int e = 0; e < 8; ++e) {
            int g = e * 256 + tid;
            int k = g & 31, r = g >> 5;
            As[k][r] = A[(size_t)(bm + r) * K + k0 + k];
            Ws[k][r] = Wt[(size_t)(bn + r) * K + k0 + k];
        }
        __syncthreads();
#pragma unroll
        for (int kk = 0; kk < 32; ++kk) {
            float4 av = *(const float4*)(&As[kk][ty * 4]);
            float4 wv = *(const float4*)(&Ws[kk][tx * 4]);
            acc[0][0] = fmaf(av.x, wv.x, acc[0][0]);
            acc[0][1] = fmaf(av.x, wv.y, acc[0][1]);
            acc[0][2] = fmaf(av.x, wv.z, acc[0][2]);
            acc[0][3] = fmaf(av.x, wv.w, acc[0][3]);
            acc[1][0] = fmaf(av.y, wv.x, acc[1][0]);
            acc[1][1] = fmaf(av.y, wv.y, acc[1][1]);
            acc[1][2] = fmaf(av.y, wv.z, acc[1][2]);
            acc[1][3] = fmaf(av.y, wv.w, acc[1][3]);
            acc[2][0] = fmaf(av.z, wv.x, acc[2][0]);
            acc[2][1] = fmaf(av.z, wv.y, acc[2][1]);
            acc[2][2] = fmaf(av.z, wv.z, acc[2][2]);
            acc[2][3] = fmaf(av.z, wv.w, acc[2][3]);
            acc[3][0] = fmaf(av.w, wv.x, acc[3][0]);
            acc[3][1] = fmaf(av.w, wv.y, acc[3][1]);
            acc[3][2] = fmaf(av.w, wv.z, acc[3][2]);
            acc[3][3] = fmaf(av.w, wv.w, acc[3][3]);
        }
        __syncthreads();
    }
    float* p = part + (size_t)blockIdx.z * M * N;
#pragma unroll
    for (int i = 0; i < 4; ++i) {
        float4 v = make_float4(acc[i][0], acc[i][1], acc[i][2], acc[i][3]);
        *(float4*)&p[(size_t)(bm + ty * 4 + i) * N + (bn + tx * 4)] = v;
    }
}

template <int SPLIT>
__global__ void fc_reduce(const float* __restrict__ part, const float* __restrict__ bias,
                          float* __restrict__ C, int MN, int N, int relu) {
    int i = blockIdx.x * 256 + threadIdx.x;
    if (i >= MN) return;
    float s = bias[i % N];
#pragma unroll
    for (int z = 0; z < SPLIT; ++z) s += part[(size_t)z * MN + i];
    C[i] = relu ? fmaxf(s, 0.f) : s;
}

// ---------------------------------------------------------------------------
// fc3: M=128, N=10, K=1024. One wave per output element.
// ---------------------------------------------------------------------------
__global__ __launch_bounds__(256) void fc3_kernel(const float* __restrict__ A,
                                                  const float* __restrict__ Wt,
                                                  const float* __restrict__ bias,
                                                  float* __restrict__ C) {
    int gid = blockIdx.x * 256 + threadIdx.x;
    int wid = gid >> 6;
    int lane = gid & 63;
    int m = wid / 10, n = wid - m * 10;
    const float4* a = (const float4*)(A + (size_t)m * 1024);
    const float4* w = (const float4*)(Wt + (size_t)n * 1024);
    float s = 0.f;
#pragma unroll
    for (int it = 0; it < 4; ++it) {
        float4 av = a[it * 64 + lane];
        float4 wv = w[it * 64 + lane];
        s += av.x * wv.x + av.y * wv.y + av.z * wv.z + av.w * wv.w;
    }
#pragma unroll
    for (int off = 32; off; off >>= 1) s += __shfl_xor(s, off);
    if (lane == 0) C[wid] = s + bias[n];
}

// ---------------------------------------------------------------------------
extern "C" void kernel_launch(void* const* d_in, const int* in_sizes, int n_in,
                              void* d_out, int out_size, void* d_ws, size_t ws_size,
                              hipStream_t stream) {
    const float* x   = (const float*)d_in[0];
    const float* bw1 = (const float*)d_in[1];
    const float* sw1 = (const float*)d_in[2];
    const float* sc1 = (const float*)d_in[3];
    const float* bw2 = (const float*)d_in[4];
    const float* sw2 = (const float*)d_in[5];
    const float* sc2 = (const float*)d_in[6];
    const float* bw3 = (const float*)d_in[7];
    const float* sw3 = (const float*)d_in[8];
    const float* sc3 = (const float*)d_in[9];
    const float* bw4 = (const float*)d_in[10];
    const float* sw4 = (const float*)d_in[11];
    const float* sc4 = (const float*)d_in[12];
    const float* w1  = (const float*)d_in[13];
    const float* b1  = (const float*)d_in[14];
    const float* w2  = (const float*)d_in[15];
    const float* b2  = (const float*)d_in[16];
    const float* w3  = (const float*)d_in[17];
    const float* b3  = (const float*)d_in[18];

    float* ws  = (float*)d_ws;
    float* wp1 = ws;           // [0,972)
    float* wp2 = ws + 972;     // [972,3564)
    float* wp3 = ws + 3564;    // [3564,13932)
    float* wp4 = ws + 13932;   // [13932,55404)
    float* base = ws + 65536;
    // liveness-packed activation buffers (floats from base):
    float* SP2    = base;              // [0, 4718592)        (B,4,9,1024)
    float* SP3    = base + 4718592;    // [4718592, 7077888)  (B,8,9,256)
    float* SP4    = base;              // [0, 4718592)        (B,16,9,256) over dead SP2
    float* pooled = base + 4718592;    // [4718592, 4980736)  (B,2048) over dead SP3
    float* part1  = base + 4980736;    // [4980736, 7077888)  8x(128,2048)
    float* fc1o   = base;              // [0, 262144)         over dead SP4
    float* part2  = base + 262144;     // [262144, 1310720)   8x(128,1024)
    float* fc2o   = base + 1310720;    // [1310720, 1441792)
    // peak = (65536 + 7077888) * 4B = 28.6 MB

    pack_all<<<(55404 + 255) / 256, 256, 0, stream>>>(bw1, sw1, sc1, bw2, sw2, sc2,
                                                      bw3, sw3, sc3, bw4, sw4, sc4, ws);

    // conv1: x -> SP2 planar
    conv1_kernel<<<512, 256, 0, stream>>>(x, wp1, SP2);
    // conv2 + pool1 + spline: SP2 -> SP3. 128 imgs x 4 strips
    conv2_pool<<<512, 256, 0, stream>>>(SP2, wp2, SP3);
    // conv3 + spline: SP3 -> SP4. 128 imgs x 4 cout-groups of 4
    conv3_kernel<4><<<dim3(128, 4), 256, 0, stream>>>(SP3, wp3, SP4);
    // conv4 + pool2: SP4 -> pooled. 128 imgs x 4 cout-groups of 8
    conv4_pool<8><<<dim3(128, 4), 256, 0, stream>>>(SP4, wp4, pooled);
    // fc1: relu(pooled @ w1.T + b1), split-K=8
    fc_big<8><<<dim3(32, 2, 8), 256, 0, stream>>>(pooled, w1, part1, 128, 2048, 2048);
    fc_reduce<8><<<1024, 256, 0, stream>>>(part1, b1, fc1o, 262144, 2048, 1);
    // fc2: relu(fc1o @ w2.T + b2), split-K=8
    fc_big<8><<<dim3(16, 2, 8), 256, 0, stream>>>(fc1o, w2, part2, 128, 1024, 2048);
    fc_reduce<8><<<512, 256, 0, stream>>>(part2, b2, fc2o, 131072, 1024, 1);
    // fc3
    fc3_kernel<<<320, 256, 0, stream>>>(fc2o, w3, b3, (float*)d_out);
}

// Round 7
// 260.808 us; speedup vs baseline: 2.6573x; 2.3239x over previous
//
#include <hip/hip_runtime.h>

#define BATCH 128
#define AST 88  // padded-A LDS row stride in ushorts (176B: 16B-aligned, ~2-way banks)

typedef __attribute__((ext_vector_type(8))) short bf16x8;
typedef __attribute__((ext_vector_type(16))) float f32x16;

// ---------------------------------------------------------------------------
// Spline activation: act[0] = silu(x), act[1..8] = cubic B-spline bases
// ---------------------------------------------------------------------------
__device__ __forceinline__ void spline_acts(float xv, float act[9]) {
    act[0] = xv * (1.0f / (1.0f + __expf(-xv)));  // silu
    float g[12];
#pragma unroll
    for (int i = 0; i < 12; ++i) g[i] = (float)(i - 3) * 0.4f - 1.0f;
    float bb[11];
#pragma unroll
    for (int c = 0; c < 11; ++c) bb[c] = (xv >= g[c] && xv < g[c + 1]) ? 1.0f : 0.0f;
#pragma unroll
    for (int k = 1; k <= 3; ++k) {
#pragma unroll
        for (int c = 0; c + k < 11; ++c) {
            float left  = (xv - g[c]) * (1.0f / (g[c + k] - g[c])) * bb[c];
            float right = (g[c + k + 1] - xv) * (1.0f / (g[c + k + 1] - g[c + 1])) * bb[c + 1];
            bb[c] = left + right;
        }
    }
#pragma unroll
    for (int c = 0; c < 8; ++c) act[c + 1] = bb[c];
}

__device__ __constant__ float ZPAD[9] = {0.0f, 0.0f, 0.0f, 0.02083333333f,
                                         0.47916666667f, 0.47916666667f,
                                         0.02083333333f, 0.0f, 0.0f};
__device__ __forceinline__ constexpr float zpc(int j) {
    return (j == 3 || j == 6) ? 0.02083333333f
         : (j == 4 || j == 5) ? 0.47916666667f : 0.0f;
}

// bf16 hi/lo split (round-to-nearest-even); x = hi + lo + O(2^-18 x)
__device__ __forceinline__ void bf16split(float x, ushort& h, ushort& l) {
    union { float f; unsigned u; } a; a.f = x;
    unsigned r = a.u + 0x7FFF + ((a.u >> 16) & 1);
    h = (ushort)(r >> 16);
    union { unsigned u; float f; } hf; hf.u = (unsigned)h << 16;
    union { float f; unsigned u; } bres; bres.f = x - hf.f;
    unsigned r2 = bres.u + 0x7FFF + ((bres.u >> 16) & 1);
    l = (ushort)(r2 >> 16);
}

// ---------------------------------------------------------------------------
// Pack weights (fp32): wpack[(cin*9+tap)*9*O + j*O + o] = j==0 ? bw : sw*sc
// ---------------------------------------------------------------------------
__device__ __forceinline__ void pack_one(int i, const float* bw, const float* sw,
                                         const float* sc, float* out, int F, int O) {
    int o = i % O;
    int j = (i / O) % 9;
    int f = i / (9 * O);
    float v;
    if (j == 0) v = bw[o * F + f];
    else        v = sw[(o * F + f) * 8 + (j - 1)] * sc[o * F + f];
    out[i] = v;
}

__global__ void pack_all(const float* __restrict__ bw1, const float* __restrict__ sw1,
                         const float* __restrict__ sc1, const float* __restrict__ bw2,
                         const float* __restrict__ sw2, const float* __restrict__ sc2,
                         const float* __restrict__ bw3, const float* __restrict__ sw3,
                         const float* __restrict__ sc3, const float* __restrict__ bw4,
                         const float* __restrict__ sw4, const float* __restrict__ sc4,
                         float* __restrict__ ws) {
    int i = blockIdx.x * blockDim.x + threadIdx.x;
    if (i < 972)        pack_one(i,         bw1, sw1, sc1, ws,         27, 4);
    else if (i < 3564)  pack_one(i - 972,   bw2, sw2, sc2, ws + 972,   36, 8);
    else if (i < 13932) pack_one(i - 3564,  bw3, sw3, sc3, ws + 3564,  72, 16);
    else if (i < 55404) pack_one(i - 13932, bw4, sw4, sc4, ws + 13932, 144, 32);
}

// ---------------------------------------------------------------------------
// Pack MFMA B-fragments (bf16 hi/lo) in streaming frag order, plus the
// zero-pad activation row pattern (80 cols of ZPAD[c%9]).
// B-frag layout (32x32x16): value(lane l, elem i) = W[k = s*16+(l>>5)*8+i][n = l&31]
// ---------------------------------------------------------------------------
__global__ void pack_frags(const float* __restrict__ wp3, const float* __restrict__ wp4,
                           ushort* __restrict__ wpk3h, ushort* __restrict__ wpk3l,
                           ushort* __restrict__ wpk4h, ushort* __restrict__ wpk4l,
                           ushort* __restrict__ zph, ushort* __restrict__ zpl) {
    int i = blockIdx.x * 256 + threadIdx.x;
    if (i < 2880) {                       // conv3: (t,s,l)
        int l = i & 63, s = (i >> 6) % 5, t = i / 320;
#pragma unroll
        for (int e = 0; e < 8; ++e) {
            int k = s * 16 + ((l >> 5) * 8) + e;
            int o = l & 31;
            float w = 0.f;
            if (k < 72 && o < 16) {
                int cin = k / 9, j = k - cin * 9;
                w = wp3[((cin * 9 + t) * 9 + j) * 16 + o];
            }
            ushort h, lo; bf16split(w, h, lo);
            wpk3h[i * 8 + e] = h; wpk3l[i * 8 + e] = lo;
        }
    } else if (i < 2880 + 5760) {         // conv4: (p,t,s,l)
        int q = i - 2880;
        int l = q & 63, s = (q >> 6) % 5, t = (q / 320) % 9, p = q / 2880;
#pragma unroll
        for (int e = 0; e < 8; ++e) {
            int k = s * 16 + ((l >> 5) * 8) + e;
            int o = l & 31;
            float w = 0.f;
            if (k < 72) {
                int cl = k / 9, j = k - cl * 9;
                int cin = p * 8 + cl;
                w = wp4[((cin * 9 + t) * 9 + j) * 32 + o];
            }
            ushort h, lo; bf16split(w, h, lo);
            wpk4h[q * 8 + e] = h; wpk4l[q * 8 + e] = lo;
        }
    } else if (i < 2880 + 5760 + 80) {
        int c = i - 8640;
        ushort h, lo; bf16split(ZPAD[c % 9], h, lo);
        zph[c] = h; zpl[c] = lo;
    }
}

// ---------------------------------------------------------------------------
// conv1: raw x (B,3,32,32), inline splines; epilogue spline -> SP2 planar fp32
// ---------------------------------------------------------------------------
__global__ __launch_bounds__(256) void conv1_kernel(const float* __restrict__ x,
                                                    const float* __restrict__ wp,
                                                    float* __restrict__ SPout) {
    constexpr int H = 32, W = 32, HW = 1024, CIN = 3, COUT = 4;
    int n = blockIdx.x * 256 + threadIdx.x;
    int w = n % W, h = (n / W) % H, b = n / HW;
    float acc[COUT] = {};
    const float* xb = x + (size_t)b * CIN * HW;
#pragma unroll 1
    for (int cin = 0; cin < CIN; ++cin) {
        const float* xc = xb + cin * HW;
#pragma unroll
        for (int dh = 0; dh < 3; ++dh) {
            int hh = h + dh - 1;
#pragma unroll
            for (int dw = 0; dw < 3; ++dw) {
                int ww = w + dw - 1;
                bool inb = ((unsigned)hh < (unsigned)H) && ((unsigned)ww < (unsigned)W);
                float xv = inb ? xc[hh * W + ww] : 0.0f;
                float a9[9];
                spline_acts(xv, a9);
                const float* wrow = wp + (size_t)(cin * 9 + dh * 3 + dw) * 9 * COUT;
#pragma unroll
                for (int j = 0; j < 9; ++j)
#pragma unroll
                    for (int co = 0; co < COUT; ++co)
                        acc[co] = fmaf(a9[j], wrow[j * COUT + co], acc[co]);
            }
        }
    }
    int p = h * W + w;
#pragma unroll
    for (int co = 0; co < COUT; ++co) {
        float a9[9];
        spline_acts(acc[co], a9);
        float* ob = SPout + ((size_t)(b * COUT + co) * 9) * HW + p;
#pragma unroll
        for (int j = 0; j < 9; ++j) ob[j * HW] = a9[j];
    }
}

// ---------------------------------------------------------------------------
// conv2 + maxpool + spline epilogue -> writes A3 (B,256,80) bf16 hi/lo.
// SP2 (B,4,9,32,32). Block = one 8-row strip; blockIdx.y = cout group (4).
// ---------------------------------------------------------------------------
__global__ __launch_bounds__(256) void conv2_pool(const float* __restrict__ SP,
                                                  const float* __restrict__ wp,
                                                  ushort* __restrict__ A3h,
                                                  ushort* __restrict__ A3l) {
    __shared__ float lds[4 * 9 * 10 * 32];  // 46KB
    int bid = blockIdx.x;
    int strip = bid & 3, b = bid >> 2;
    int o0 = blockIdx.y * 4;
    int r0 = strip * 8;
    const float* spb = SP + (size_t)b * 4 * 9 * 1024;
#pragma unroll
    for (int e = 0; e < 12; ++e) {
        int idx = e * 256 + threadIdx.x;
        if (idx < 2880) {
            int seg = idx / 80;
            int off4 = idx % 80;
            int j = seg % 9;
            int grow = r0 - 1 + (off4 >> 3);
            int col4 = off4 & 7;
            float4 v;
            if ((unsigned)grow < 32u)
                v = *(const float4*)(spb + (size_t)seg * 1024 + grow * 32 + col4 * 4);
            else { float z = ZPAD[j]; v = make_float4(z, z, z, z); }
            *(float4*)(&lds[seg * 320 + off4 * 4]) = v;
        }
    }
    __syncthreads();

    int col = threadIdx.x & 31, lrow = threadIdx.x >> 5;
    float acc[4] = {};
#pragma unroll 1
    for (int cin = 0; cin < 4; ++cin) {
#pragma unroll
        for (int dh = 0; dh < 3; ++dh) {
            int srow = lrow + dh;
#pragma unroll
            for (int dw = 0; dw < 3; ++dw) {
                int ww = col + dw - 1;
                bool inw = (unsigned)ww < 32u;
                int wc = inw ? ww : 0;
                const float* lp = &lds[(cin * 9) * 320 + srow * 32 + wc];
                const float* wrow = wp + (size_t)(cin * 9 + dh * 3 + dw) * 72;
                float s[9];
#pragma unroll
                for (int j = 0; j < 9; ++j) s[j] = lp[j * 320];
#pragma unroll
                for (int j = 0; j < 9; ++j) {
                    float sj = inw ? s[j] : zpc(j);
#pragma unroll
                    for (int co = 0; co < 4; ++co)
                        acc[co] = fmaf(sj, wrow[j * 8 + o0 + co], acc[co]);
                }
            }
        }
    }

    // 2x2 maxpool within wave
    bool act = ((col & 1) == 0) && ((lrow & 1) == 0);
    int ph = (r0 + lrow) >> 1, pw = col >> 1;
#pragma unroll
    for (int co = 0; co < 4; ++co) {
        float v = acc[co];
        v = fmaxf(v, __shfl_xor(v, 1));
        v = fmaxf(v, __shfl_xor(v, 32));
        acc[co] = v;
    }
    if (act) {
        int px = ph * 16 + pw;
        unsigned rh[18] = {}, rl[18] = {};
#pragma unroll
        for (int co = 0; co < 4; ++co) {
            float a9[9];
            spline_acts(acc[co], a9);
#pragma unroll
            for (int j = 0; j < 9; ++j) {
                ushort h, l2; bf16split(a9[j], h, l2);
                int c = co * 9 + j;
                if (c & 1) { rh[c >> 1] |= (unsigned)h << 16; rl[c >> 1] |= (unsigned)l2 << 16; }
                else       { rh[c >> 1] |= h;                  rl[c >> 1] |= l2; }
            }
        }
        unsigned* gh = (unsigned*)(A3h + ((size_t)b * 256 + px) * 80 + o0 * 9);
        unsigned* gl = (unsigned*)(A3l + ((size_t)b * 256 + px) * 80 + o0 * 9);
#pragma unroll
        for (int k = 0; k < 18; ++k) { gh[k] = rh[k]; gl[k] = rl[k]; }
        if (o0) {  // this group also zeroes pad cols 72..79
            unsigned* ph2 = (unsigned*)(A3h + ((size_t)b * 256 + px) * 80 + 72);
            unsigned* pl2 = (unsigned*)(A3l + ((size_t)b * 256 + px) * 80 + 72);
#pragma unroll
            for (int k = 0; k < 4; ++k) { ph2[k] = 0u; pl2[k] = 0u; }
        }
    }
}

// ---------------------------------------------------------------------------
// MFMA conv over padded-A LDS. A-global: (B, NPH, 256, 80) bf16 hi/lo.
// B-frags: (NPH,9,5,64,8) hi/lo. 32x32x16_bf16, bf16x3 split precision.
// POOL=0: spline epilogue -> Oh/Ol = next A (B,2,256,80).
// POOL=1: 2x2 maxpool -> pooled (B, NCO*64) fp32.
// ---------------------------------------------------------------------------
template <int NPH, int NCO, int POOL>
__global__ __launch_bounds__(256) void conv_mfma(
    const ushort* __restrict__ Agh, const ushort* __restrict__ Agl,
    const ushort* __restrict__ Bgh, const ushort* __restrict__ Bgl,
    const ushort* __restrict__ zph, const ushort* __restrict__ zpl,
    ushort* __restrict__ Oh, ushort* __restrict__ Ol,
    float* __restrict__ pooled) {
    __shared__ ushort AH[324 * AST];  // 57KB
    __shared__ ushort AL[324 * AST];  // 57KB
    const int tid = threadIdx.x;
    const int b = blockIdx.x;
    const int lane = tid & 63, wv = tid >> 6;

    f32x16 acc0, acc1;
#pragma unroll
    for (int i = 0; i < 16; ++i) { acc0[i] = 0.f; acc1[i] = 0.f; }

    const int r0 = wv * 64 + (lane & 31);
    const int r1 = r0 + 32;
    const int rp0 = ((r0 >> 4) + 1) * 18 + (r0 & 15) + 1;
    const int rp1 = ((r1 >> 4) + 1) * 18 + (r1 & 15) + 1;
    const int koff = (lane >> 5) * 8;

#pragma unroll 1
    for (int p = 0; p < NPH; ++p) {
        if (p) __syncthreads();
        const ushort* ash = Agh + ((size_t)b * NPH + p) * 256 * 80;
        const ushort* asl = Agl + ((size_t)b * NPH + p) * 256 * 80;
#pragma unroll
        for (int e = 0; e < 10; ++e) {
            int g4 = e * 256 + tid;
            int row = g4 / 10, ch = g4 - row * 10;
            int rp = ((row >> 4) + 1) * 18 + (row & 15) + 1;
            *(uint4*)(&AH[rp * AST + ch * 8]) = *(const uint4*)(ash + (size_t)g4 * 8);
            *(uint4*)(&AL[rp * AST + ch * 8]) = *(const uint4*)(asl + (size_t)g4 * 8);
        }
        for (int rr = tid; rr < 324; rr += 256) {
            int y = rr / 18, xx = rr - y * 18;
            if (y == 0 || y == 17 || xx == 0 || xx == 17) {
#pragma unroll
                for (int ch = 0; ch < 10; ++ch) {
                    *(uint4*)(&AH[rr * AST + ch * 8]) = *(const uint4*)(zph + ch * 8);
                    *(uint4*)(&AL[rr * AST + ch * 8]) = *(const uint4*)(zpl + ch * 8);
                }
            }
        }
        __syncthreads();

        const ushort* bsh = Bgh + (size_t)p * 2880 * 8;
        const ushort* bsl = Bgl + (size_t)p * 2880 * 8;
#pragma unroll 1
        for (int t = 0; t < 9; ++t) {
            const int dA = ((t / 3) - 1) * 18 + (t % 3) - 1;
#pragma unroll
            for (int s = 0; s < 5; ++s) {
                bf16x8 a0h = *(const bf16x8*)(&AH[(rp0 + dA) * AST + s * 16 + koff]);
                bf16x8 a0l = *(const bf16x8*)(&AL[(rp0 + dA) * AST + s * 16 + koff]);
                bf16x8 a1h = *(const bf16x8*)(&AH[(rp1 + dA) * AST + s * 16 + koff]);
                bf16x8 a1l = *(const bf16x8*)(&AL[(rp1 + dA) * AST + s * 16 + koff]);
                const ushort* bph = bsh + (size_t)((t * 5 + s) * 64 + lane) * 8;
                const ushort* bpl = bsl + (size_t)((t * 5 + s) * 64 + lane) * 8;
                bf16x8 bh = *(const bf16x8*)bph;
                bf16x8 bl = *(const bf16x8*)bpl;
                acc0 = __builtin_amdgcn_mfma_f32_32x32x16_bf16(a0h, bh, acc0, 0, 0, 0);
                acc1 = __builtin_amdgcn_mfma_f32_32x32x16_bf16(a1h, bh, acc1, 0, 0, 0);
                acc0 = __builtin_amdgcn_mfma_f32_32x32x16_bf16(a0h, bl, acc0, 0, 0, 0);
                acc1 = __builtin_amdgcn_mfma_f32_32x32x16_bf16(a1h, bl, acc1, 0, 0, 0);
                acc0 = __builtin_amdgcn_mfma_f32_32x32x16_bf16(a0l, bh, acc0, 0, 0, 0);
                acc1 = __builtin_amdgcn_mfma_f32_32x32x16_bf16(a1l, bh, acc1, 0, 0, 0);
            }
        }
    }
    __syncthreads();

    // transpose acc -> LDS fp32 [NCO][257]
    float* fl = (float*)AH;
    {
        int ccol = lane & 31;
        if (ccol < NCO) {
#pragma unroll
            for (int r = 0; r < 16; ++r) {
                int row = (r & 3) + 8 * (r >> 2) + 4 * (lane >> 5);
                fl[ccol * 257 + wv * 64 + row] = acc0[r];
                fl[ccol * 257 + wv * 64 + 32 + row] = acc1[r];
            }
        }
    }
    __syncthreads();

    if (POOL == 1) {
#pragma unroll
        for (int e = 0; e < NCO * 64 / 256; ++e) {
            int idx = e * 256 + tid;
            int co = idx >> 6, pp = idx & 63;
            int p2 = pp >> 3, w2 = pp & 7;
            const float* fb = fl + co * 257 + p2 * 32 + w2 * 2;
            float m = fmaxf(fmaxf(fb[0], fb[1]), fmaxf(fb[16], fb[17]));
            pooled[(size_t)b * (NCO * 64) + idx] = m;
        }
    } else {
        int px = tid;
#pragma unroll 1
        for (int p2 = 0; p2 < 2; ++p2) {
            // full 80-col row: 40 packed words (FIX: was rh[20] + wrong stride)
            unsigned rh[40], rl[40];
#pragma unroll
            for (int k = 0; k < 40; ++k) { rh[k] = 0u; rl[k] = 0u; }
#pragma unroll
            for (int co = 0; co < 8; ++co) {
                float v = fl[(p2 * 8 + co) * 257 + px];
                float a9[9];
                spline_acts(v, a9);
#pragma unroll
                for (int j = 0; j < 9; ++j) {
                    ushort h, l2; bf16split(a9[j], h, l2);
                    int c = co * 9 + j;
                    if (c & 1) { rh[c >> 1] |= (unsigned)h << 16; rl[c >> 1] |= (unsigned)l2 << 16; }
                    else       { rh[c >> 1] |= h;                  rl[c >> 1] |= l2; }
                }
            }
            ushort* oh = Oh + ((size_t)(b * 2 + p2) * 256 + px) * 80;
            ushort* ol = Ol + ((size_t)(b * 2 + p2) * 256 + px) * 80;
#pragma unroll
            for (int ch = 0; ch < 10; ++ch) {
                uint4 vh = {rh[ch * 4], rh[ch * 4 + 1], rh[ch * 4 + 2], rh[ch * 4 + 3]};
                uint4 vl = {rl[ch * 4], rl[ch * 4 + 1], rl[ch * 4 + 2], rl[ch * 4 + 3]};
                *(uint4*)(oh + ch * 8) = vh;
                *(uint4*)(ol + ch * 8) = vl;
            }
        }
    }
}

// ---------------------------------------------------------------------------
// fc_big: 64x64 tile, 4x4/thread, K_TILE=32, split-K via blockIdx.z.
// ---------------------------------------------------------------------------
template <int SPLIT>
__global__ __launch_bounds__(256) void fc_big(const float* __restrict__ A,
                                              const float* __restrict__ Wt,
                                              float* __restrict__ part,
                                              int M, int N, int K) {
    __shared__ float As[32][68];
    __shared__ float Ws[32][68];
    const int tid = threadIdx.x;
    const int tx = tid & 15, ty = tid >> 4;
    const int bm = blockIdx.y * 64, bn = blockIdx.x * 64;
    const int kc = K / SPLIT;
    const int kbeg = blockIdx.z * kc;
    float acc[4][4] = {};
    for (int k0 = kbeg; k0 < kbeg + kc; k0 += 32) {
#pragma unroll
        for (int e = 0; e < 8; ++e) {
            int g = e * 256 + tid;
            int k = g & 31, r = g >> 5;
            As[k][r] = A[(size_t)(bm + r) * K + k0 + k];
            Ws[k][r] = Wt[(size_t)(bn + r) * K + k0 + k];
        }
        __syncthreads();
#pragma unroll
        for (int kk = 0; kk < 32; ++kk) {
            float4 av = *(const float4*)(&As[kk][ty * 4]);
            float4 wv = *(const float4*)(&Ws[kk][tx * 4]);
            acc[0][0] = fmaf(av.x, wv.x, acc[0][0]);
            acc[0][1] = fmaf(av.x, wv.y, acc[0][1]);
            acc[0][2] = fmaf(av.x, wv.z, acc[0][2]);
            acc[0][3] = fmaf(av.x, wv.w, acc[0][3]);
            acc[1][0] = fmaf(av.y, wv.x, acc[1][0]);
            acc[1][1] = fmaf(av.y, wv.y, acc[1][1]);
            acc[1][2] = fmaf(av.y, wv.z, acc[1][2]);
            acc[1][3] = fmaf(av.y, wv.w, acc[1][3]);
            acc[2][0] = fmaf(av.z, wv.x, acc[2][0]);
            acc[2][1] = fmaf(av.z, wv.y, acc[2][1]);
            acc[2][2] = fmaf(av.z, wv.z, acc[2][2]);
            acc[2][3] = fmaf(av.z, wv.w, acc[2][3]);
            acc[3][0] = fmaf(av.w, wv.x, acc[3][0]);
            acc[3][1] = fmaf(av.w, wv.y, acc[3][1]);
            acc[3][2] = fmaf(av.w, wv.z, acc[3][2]);
            acc[3][3] = fmaf(av.w, wv.w, acc[3][3]);
        }
        __syncthreads();
    }
    float* p = part + (size_t)blockIdx.z * M * N;
#pragma unroll
    for (int i = 0; i < 4; ++i) {
        float4 v = make_float4(acc[i][0], acc[i][1], acc[i][2], acc[i][3]);
        *(float4*)&p[(size_t)(bm + ty * 4 + i) * N + (bn + tx * 4)] = v;
    }
}

template <int SPLIT>
__global__ void fc_reduce(const float* __restrict__ part, const float* __restrict__ bias,
                          float* __restrict__ C, int MN, int N, int relu) {
    int i = blockIdx.x * 256 + threadIdx.x;
    if (i >= MN) return;
    float s = bias[i % N];
#pragma unroll
    for (int z = 0; z < SPLIT; ++z) s += part[(size_t)z * MN + i];
    C[i] = relu ? fmaxf(s, 0.f) : s;
}

__global__ __launch_bounds__(256) void fc3_kernel(const float* __restrict__ A,
                                                  const float* __restrict__ Wt,
                                                  const float* __restrict__ bias,
                                                  float* __restrict__ C) {
    int gid = blockIdx.x * 256 + threadIdx.x;
    int wid = gid >> 6;
    int lane = gid & 63;
    int m = wid / 10, n = wid - m * 10;
    const float4* a = (const float4*)(A + (size_t)m * 1024);
    const float4* w = (const float4*)(Wt + (size_t)n * 1024);
    float s = 0.f;
#pragma unroll
    for (int it = 0; it < 4; ++it) {
        float4 av = a[it * 64 + lane];
        float4 wv = w[it * 64 + lane];
        s += av.x * wv.x + av.y * wv.y + av.z * wv.z + av.w * wv.w;
    }
#pragma unroll
    for (int off = 32; off; off >>= 1) s += __shfl_xor(s, off);
    if (lane == 0) C[wid] = s + bias[n];
}

// ---------------------------------------------------------------------------
extern "C" void kernel_launch(void* const* d_in, const int* in_sizes, int n_in,
                              void* d_out, int out_size, void* d_ws, size_t ws_size,
                              hipStream_t stream) {
    const float* x   = (const float*)d_in[0];
    const float* bw1 = (const float*)d_in[1];
    const float* sw1 = (const float*)d_in[2];
    const float* sc1 = (const float*)d_in[3];
    const float* bw2 = (const float*)d_in[4];
    const float* sw2 = (const float*)d_in[5];
    const float* sc2 = (const float*)d_in[6];
    const float* bw3 = (const float*)d_in[7];
    const float* sw3 = (const float*)d_in[8];
    const float* sc3 = (const float*)d_in[9];
    const float* bw4 = (const float*)d_in[10];
    const float* sw4 = (const float*)d_in[11];
    const float* sc4 = (const float*)d_in[12];
    const float* w1  = (const float*)d_in[13];
    const float* b1  = (const float*)d_in[14];
    const float* w2  = (const float*)d_in[15];
    const float* b2  = (const float*)d_in[16];
    const float* w3  = (const float*)d_in[17];
    const float* b3  = (const float*)d_in[18];

    float*  wsf = (float*)d_ws;
    ushort* wsu = (ushort*)d_ws;
    float* wp1 = wsf;            // fp32 packed weights [0, 55404)
    float* wp2 = wsf + 972;
    float* wp3 = wsf + 3564;
    float* wp4 = wsf + 13932;
    ushort* wpk3h = wsu + 110848;     // 23040 each
    ushort* wpk3l = wsu + 133888;
    ushort* wpk4h = wsu + 156928;     // 46080 each
    ushort* wpk4l = wsu + 203008;
    ushort* zph   = wsu + 249088;     // 80
    ushort* zpl   = wsu + 249168;
    // activations (liveness-packed):
    float*  SP2  = wsf + 262144;       // byte [1M, 19.9M)  (B,4,9,1024) fp32
    ushort* A4h  = wsu + 524288;       // byte [1M, 11.5M)  over SP2 after it dies
    ushort* A4l  = wsu + 5767168;      // byte [11.5M, 22.0M)
    ushort* A3h  = wsu + 11010048;     // byte [22.0M, 27.3M)
    ushort* A3l  = wsu + 13631488;     // byte [27.3M, 32.5M)
    float* pooled = wsf + 5505024;     // byte [22.0M, 23.1M) over dead A3h
    float* part1  = wsf + 5767168;     // byte [23.1M, 31.5M)
    float* fc1o   = wsf + 262144;      // byte [1M, 2M)  over dead A4
    float* part2  = wsf + 524288;      // byte [2M, 6.3M)
    float* fc2o   = wsf + 1572864;     // byte [6.3M, 6.8M)

    pack_all<<<(55404 + 255) / 256, 256, 0, stream>>>(bw1, sw1, sc1, bw2, sw2, sc2,
                                                      bw3, sw3, sc3, bw4, sw4, sc4, wsf);
    pack_frags<<<35, 256, 0, stream>>>(wp3, wp4, wpk3h, wpk3l, wpk4h, wpk4l, zph, zpl);

    // conv1: x -> SP2 planar fp32
    conv1_kernel<<<512, 256, 0, stream>>>(x, wp1, SP2);
    // conv2 + pool + spline -> A3 bf16 hi/lo. 128 imgs x 4 strips x 2 cout-groups
    conv2_pool<<<dim3(512, 2), 256, 0, stream>>>(SP2, wp2, A3h, A3l);
    // conv3 MFMA + spline epilogue -> A4
    conv_mfma<1, 16, 0><<<128, 256, 0, stream>>>(A3h, A3l, wpk3h, wpk3l, zph, zpl,
                                                 A4h, A4l, nullptr);
    // conv4 MFMA + pool -> pooled (B,2048)
    conv_mfma<2, 32, 1><<<128, 256, 0, stream>>>(A4h, A4l, wpk4h, wpk4l, zph, zpl,
                                                 nullptr, nullptr, pooled);
    // fc1: relu(pooled @ w1.T + b1), split-K=8
    fc_big<8><<<dim3(32, 2, 8), 256, 0, stream>>>(pooled, w1, part1, 128, 2048, 2048);
    fc_reduce<8><<<1024, 256, 0, stream>>>(part1, b1, fc1o, 262144, 2048, 1);
    // fc2: relu(fc1o @ w2.T + b2), split-K=8
    fc_big<8><<<dim3(16, 2, 8), 256, 0, stream>>>(fc1o, w2, part2, 128, 1024, 2048);
    fc_reduce<8><<<512, 256, 0, stream>>>(part2, b2, fc2o, 131072, 1024, 1);
    // fc3
    fc3_kernel<<<320, 256, 0, stream>>>(fc2o, w3, b3, (float*)d_out);
}

// Round 8
// 174.602 us; speedup vs baseline: 3.9693x; 1.4937x over previous
//
#include <hip/hip_runtime.h>

#define BATCH 128
#define AST 88  // conv_mfma padded-A LDS row stride in ushorts

typedef __attribute__((ext_vector_type(8))) short bf16x8;
typedef __attribute__((ext_vector_type(16))) float f32x16;

// ---------------------------------------------------------------------------
// Spline activation: act[0] = silu(x), act[1..8] = cubic B-spline bases
// ---------------------------------------------------------------------------
__device__ __forceinline__ void spline_acts(float xv, float act[9]) {
    act[0] = xv * (1.0f / (1.0f + __expf(-xv)));  // silu
    float g[12];
#pragma unroll
    for (int i = 0; i < 12; ++i) g[i] = (float)(i - 3) * 0.4f - 1.0f;
    float bb[11];
#pragma unroll
    for (int c = 0; c < 11; ++c) bb[c] = (xv >= g[c] && xv < g[c + 1]) ? 1.0f : 0.0f;
#pragma unroll
    for (int k = 1; k <= 3; ++k) {
#pragma unroll
        for (int c = 0; c + k < 11; ++c) {
            float left  = (xv - g[c]) * (1.0f / (g[c + k] - g[c])) * bb[c];
            float right = (g[c + k + 1] - xv) * (1.0f / (g[c + k + 1] - g[c + 1])) * bb[c + 1];
            bb[c] = left + right;
        }
    }
#pragma unroll
    for (int c = 0; c < 8; ++c) act[c + 1] = bb[c];
}

__device__ __constant__ float ZPAD[9] = {0.0f, 0.0f, 0.0f, 0.02083333333f,
                                         0.47916666667f, 0.47916666667f,
                                         0.02083333333f, 0.0f, 0.0f};

// bf16 hi/lo split (round-to-nearest-even); x = hi + lo + O(2^-18 x)
__device__ __forceinline__ void bf16split(float x, ushort& h, ushort& l) {
    union { float f; unsigned u; } a; a.f = x;
    unsigned r = a.u + 0x7FFF + ((a.u >> 16) & 1);
    h = (ushort)(r >> 16);
    union { unsigned u; float f; } hf; hf.u = (unsigned)h << 16;
    union { float f; unsigned u; } bres; bres.f = x - hf.f;
    unsigned r2 = bres.u + 0x7FFF + ((bres.u >> 16) & 1);
    l = (ushort)(r2 >> 16);
}

// ---------------------------------------------------------------------------
// Pack weights (fp32): wpack[(cin*9+tap)*9*O + j*O + o] = j==0 ? bw : sw*sc
// ---------------------------------------------------------------------------
__device__ __forceinline__ void pack_one(int i, const float* bw, const float* sw,
                                         const float* sc, float* out, int F, int O) {
    int o = i % O;
    int j = (i / O) % 9;
    int f = i / (9 * O);
    float v;
    if (j == 0) v = bw[o * F + f];
    else        v = sw[(o * F + f) * 8 + (j - 1)] * sc[o * F + f];
    out[i] = v;
}

__global__ void pack_all(const float* __restrict__ bw1, const float* __restrict__ sw1,
                         const float* __restrict__ sc1, const float* __restrict__ bw2,
                         const float* __restrict__ sw2, const float* __restrict__ sc2,
                         const float* __restrict__ bw3, const float* __restrict__ sw3,
                         const float* __restrict__ sc3, const float* __restrict__ bw4,
                         const float* __restrict__ sw4, const float* __restrict__ sc4,
                         float* __restrict__ ws) {
    int i = blockIdx.x * blockDim.x + threadIdx.x;
    if (i < 972)        pack_one(i,         bw1, sw1, sc1, ws,         27, 4);
    else if (i < 3564)  pack_one(i - 972,   bw2, sw2, sc2, ws + 972,   36, 8);
    else if (i < 13932) pack_one(i - 3564,  bw3, sw3, sc3, ws + 3564,  72, 16);
    else if (i < 55404) pack_one(i - 13932, bw4, sw4, sc4, ws + 13932, 144, 32);
}

// ---------------------------------------------------------------------------
// Pack MFMA B-fragments (bf16 hi/lo) for all 4 conv layers + zp pattern.
// B-frag (32x32x16): value(lane l, elem e) = W[k = s*16+(l>>5)*8+e][o = l&31]
// Feature order k = cin*9 + j (per tap t).
// ---------------------------------------------------------------------------
__global__ void pack_frags(const float* __restrict__ wp1, const float* __restrict__ wp2,
                           const float* __restrict__ wp3, const float* __restrict__ wp4,
                           ushort* __restrict__ k1h, ushort* __restrict__ k1l,
                           ushort* __restrict__ k2h, ushort* __restrict__ k2l,
                           ushort* __restrict__ k3h, ushort* __restrict__ k3l,
                           ushort* __restrict__ k4h, ushort* __restrict__ k4l,
                           ushort* __restrict__ zph, ushort* __restrict__ zpl) {
    int i = blockIdx.x * 256 + threadIdx.x;
    if (i < 1152) {                            // conv1: (t, 2 ksteps, l)
        int l = i & 63, s = (i >> 6) & 1, t = i / 128;
#pragma unroll
        for (int e = 0; e < 8; ++e) {
            int k = s * 16 + ((l >> 5) * 8) + e, o = l & 31;
            float w = 0.f;
            if (k < 27 && o < 4) w = wp1[(((k / 9) * 9 + t) * 9 + (k % 9)) * 4 + o];
            ushort h, lo; bf16split(w, h, lo);
            k1h[i * 8 + e] = h; k1l[i * 8 + e] = lo;
        }
    } else if (i < 2880) {                     // conv2: (t, 3 ksteps, l)
        int q = i - 1152;
        int l = q & 63, s = (q >> 6) % 3, t = q / 192;
#pragma unroll
        for (int e = 0; e < 8; ++e) {
            int k = s * 16 + ((l >> 5) * 8) + e, o = l & 31;
            float w = 0.f;
            if (k < 36 && o < 8) w = wp2[(((k / 9) * 9 + t) * 9 + (k % 9)) * 8 + o];
            ushort h, lo; bf16split(w, h, lo);
            k2h[q * 8 + e] = h; k2l[q * 8 + e] = lo;
        }
    } else if (i < 5760) {                     // conv3: (t, 5 ksteps, l)
        int q = i - 2880;
        int l = q & 63, s = (q >> 6) % 5, t = q / 320;
#pragma unroll
        for (int e = 0; e < 8; ++e) {
            int k = s * 16 + ((l >> 5) * 8) + e, o = l & 31;
            float w = 0.f;
            if (k < 72 && o < 16) w = wp3[(((k / 9) * 9 + t) * 9 + (k % 9)) * 16 + o];
            ushort h, lo; bf16split(w, h, lo);
            k3h[q * 8 + e] = h; k3l[q * 8 + e] = lo;
        }
    } else if (i < 11520) {                    // conv4: (phase, t, 5 ksteps, l)
        int q = i - 5760;
        int l = q & 63, s = (q >> 6) % 5, t = (q / 320) % 9, p = q / 2880;
#pragma unroll
        for (int e = 0; e < 8; ++e) {
            int k = s * 16 + ((l >> 5) * 8) + e, o = l & 31;
            float w = 0.f;
            if (k < 72) w = wp4[(((p * 8 + k / 9) * 9 + t) * 9 + (k % 9)) * 32 + o];
            ushort h, lo; bf16split(w, h, lo);
            k4h[q * 8 + e] = h; k4l[q * 8 + e] = lo;
        }
    } else if (i < 11600) {
        int c = i - 11520;
        ushort h, lo; bf16split(ZPAD[c % 9], h, lo);
        zph[c] = h; zpl[c] = lo;
    }
}

// ---------------------------------------------------------------------------
// spline_x: raw x (B,3,32,32) -> A1 (B,1024,28) bf16 hi/lo (col 27 = 0 pad)
// ---------------------------------------------------------------------------
__global__ __launch_bounds__(256) void spline_x(const float* __restrict__ x,
                                                ushort* __restrict__ A1h,
                                                ushort* __restrict__ A1l) {
    int i = blockIdx.x * 256 + threadIdx.x;  // b*1024 + px
    int px = i & 1023, b = i >> 10;
    const float* xb = x + (size_t)b * 3072 + px;
    unsigned rh[14] = {}, rl[14] = {};
#pragma unroll
    for (int cin = 0; cin < 3; ++cin) {
        float a9[9];
        spline_acts(xb[cin * 1024], a9);
#pragma unroll
        for (int j = 0; j < 9; ++j) {
            ushort h, l2; bf16split(a9[j], h, l2);
            int c = cin * 9 + j;
            if (c & 1) { rh[c >> 1] |= (unsigned)h << 16; rl[c >> 1] |= (unsigned)l2 << 16; }
            else       { rh[c >> 1] |= h;                  rl[c >> 1] |= l2; }
        }
    }
    ushort* oh = A1h + (size_t)i * 28;
    ushort* ol = A1l + (size_t)i * 28;
#pragma unroll
    for (int w = 0; w < 7; ++w) {
        *(uint2*)(oh + w * 4) = make_uint2(rh[2 * w], rh[2 * w + 1]);
        *(uint2*)(ol + w * 4) = make_uint2(rl[2 * w], rl[2 * w + 1]);
    }
}

// ---------------------------------------------------------------------------
// Strip MFMA conv for 32x32 layers. Block = one 8-row strip of one image.
// A-global: (B, 1024, KG) bf16 hi/lo. LDS: padded 10x34 px, ASTR stride.
// B-frags: (9, KSTEPS, 64, 8). EPI=0: spline -> A2 (36 cols).
// EPI=1: 2x2 pool + spline -> A3 (80 cols, pad 72..79 = 0).
// ---------------------------------------------------------------------------
template <int KG, int CHG, int CHL, int ASTR, int KSTEPS, int NCO, int EPI>
__global__ __launch_bounds__(256) void conv_strip(
    const ushort* __restrict__ Agh, const ushort* __restrict__ Agl,
    const ushort* __restrict__ Bgh, const ushort* __restrict__ Bgl,
    const ushort* __restrict__ zph, const ushort* __restrict__ zpl,
    ushort* __restrict__ Oh, ushort* __restrict__ Ol) {
    __shared__ ushort AH[340 * ASTR];
    __shared__ ushort AL[340 * ASTR];
    const int tid = threadIdx.x;
    const int b = blockIdx.x >> 2, strip = blockIdx.x & 3;
    const int r0 = strip * 8;
    const int lane = tid & 63, wv = tid >> 6;

    // stage real rows (10 rows x 32 cols, halo rows from image or zp pattern)
    {
        const ushort* ash = Agh + (size_t)b * 1024 * KG;
        const ushort* asl = Agl + (size_t)b * 1024 * KG;
        for (int idx = tid; idx < 320 * CHL; idx += 256) {
            int pxl = idx / CHL, ch = idx - pxl * CHL;
            int lr = pxl >> 5, c = pxl & 31;
            int grow = r0 - 1 + lr;
            uint2 vh, vl;
            if (ch >= CHG) { vh = make_uint2(0u, 0u); vl = make_uint2(0u, 0u); }
            else if ((unsigned)grow < 32u) {
                vh = *(const uint2*)(ash + (size_t)(grow * 32 + c) * KG + ch * 4);
                vl = *(const uint2*)(asl + (size_t)(grow * 32 + c) * KG + ch * 4);
            } else {
                vh = *(const uint2*)(zph + ch * 4);
                vl = *(const uint2*)(zpl + ch * 4);
            }
            int spx = lr * 34 + c + 1;
            *(uint2*)(&AH[spx * ASTR + ch * 4]) = vh;
            *(uint2*)(&AL[spx * ASTR + ch * 4]) = vl;
        }
        // border cols 0 and 33, all 10 rows
        for (int idx = tid; idx < 20 * CHL; idx += 256) {
            int sel = idx / CHL, ch = idx - sel * CHL;
            int lr = sel >> 1, c = (sel & 1) ? 33 : 0;
            int spx = lr * 34 + c;
            *(uint2*)(&AH[spx * ASTR + ch * 4]) = *(const uint2*)(zph + ch * 4);
            *(uint2*)(&AL[spx * ASTR + ch * 4]) = *(const uint2*)(zpl + ch * 4);
        }
    }
    __syncthreads();

    f32x16 acc0, acc1;
#pragma unroll
    for (int i = 0; i < 16; ++i) { acc0[i] = 0.f; acc1[i] = 0.f; }

    const int p0 = wv * 64 + (lane & 31);
    const int sp0 = ((p0 >> 5) + 1) * 34 + (p0 & 31) + 1;
    const int sp1 = sp0 + 34;  // p0+32: same col, next strip row
    const int koff = (lane >> 5) * 8;

#pragma unroll 1
    for (int t = 0; t < 9; ++t) {
        const int dA = ((t / 3) - 1) * 34 + (t % 3) - 1;
#pragma unroll
        for (int s = 0; s < KSTEPS; ++s) {
            bf16x8 a0h = *(const bf16x8*)(&AH[(sp0 + dA) * ASTR + s * 16 + koff]);
            bf16x8 a0l = *(const bf16x8*)(&AL[(sp0 + dA) * ASTR + s * 16 + koff]);
            bf16x8 a1h = *(const bf16x8*)(&AH[(sp1 + dA) * ASTR + s * 16 + koff]);
            bf16x8 a1l = *(const bf16x8*)(&AL[(sp1 + dA) * ASTR + s * 16 + koff]);
            bf16x8 bh = *(const bf16x8*)(Bgh + (size_t)((t * KSTEPS + s) * 64 + lane) * 8);
            bf16x8 bl = *(const bf16x8*)(Bgl + (size_t)((t * KSTEPS + s) * 64 + lane) * 8);
            acc0 = __builtin_amdgcn_mfma_f32_32x32x16_bf16(a0h, bh, acc0, 0, 0, 0);
            acc1 = __builtin_amdgcn_mfma_f32_32x32x16_bf16(a1h, bh, acc1, 0, 0, 0);
            acc0 = __builtin_amdgcn_mfma_f32_32x32x16_bf16(a0h, bl, acc0, 0, 0, 0);
            acc1 = __builtin_amdgcn_mfma_f32_32x32x16_bf16(a1h, bl, acc1, 0, 0, 0);
            acc0 = __builtin_amdgcn_mfma_f32_32x32x16_bf16(a0l, bh, acc0, 0, 0, 0);
            acc1 = __builtin_amdgcn_mfma_f32_32x32x16_bf16(a1l, bh, acc1, 0, 0, 0);
        }
    }
    __syncthreads();

    // transpose acc -> LDS fp32 [NCO][257]
    float* fl = (float*)AH;
    {
        int ccol = lane & 31;
        if (ccol < NCO) {
#pragma unroll
            for (int r = 0; r < 16; ++r) {
                int row = (r & 3) + 8 * (r >> 2) + 4 * (lane >> 5);
                fl[ccol * 257 + wv * 64 + row] = acc0[r];
                fl[ccol * 257 + wv * 64 + 32 + row] = acc1[r];
            }
        }
    }
    __syncthreads();

    if (EPI == 0) {
        // conv1: spline epilogue -> A2 rows of 36 cols (4 couts x 9 j)
        int gpx = strip * 256 + tid;
        unsigned rh[18] = {}, rl[18] = {};
#pragma unroll
        for (int co = 0; co < 4; ++co) {
            float a9[9];
            spline_acts(fl[co * 257 + tid], a9);
#pragma unroll
            for (int j = 0; j < 9; ++j) {
                ushort h, l2; bf16split(a9[j], h, l2);
                int c = co * 9 + j;
                if (c & 1) { rh[c >> 1] |= (unsigned)h << 16; rl[c >> 1] |= (unsigned)l2 << 16; }
                else       { rh[c >> 1] |= h;                  rl[c >> 1] |= l2; }
            }
        }
        ushort* oh = Oh + ((size_t)b * 1024 + gpx) * 36;
        ushort* ol = Ol + ((size_t)b * 1024 + gpx) * 36;
#pragma unroll
        for (int w = 0; w < 9; ++w) {
            *(uint2*)(oh + w * 4) = make_uint2(rh[2 * w], rh[2 * w + 1]);
            *(uint2*)(ol + w * 4) = make_uint2(rl[2 * w], rl[2 * w + 1]);
        }
    } else {
        // conv2: 2x2 pool + spline -> A3 (80-col rows). 4 groups x 64 pooled px.
        int cg = tid >> 6, pl = tid & 63;
        int phl = pl >> 4, pw = pl & 15;
        int base = (2 * phl) * 32 + 2 * pw;
        int gpx = (4 * strip + phl) * 16 + pw;
        unsigned rh[9] = {}, rl[9] = {};
#pragma unroll
        for (int e = 0; e < 2; ++e) {
            int co = cg * 2 + e;
            const float* fb = fl + co * 257 + base;
            float m = fmaxf(fmaxf(fb[0], fb[1]), fmaxf(fb[32], fb[33]));
            float a9[9];
            spline_acts(m, a9);
#pragma unroll
            for (int j = 0; j < 9; ++j) {
                ushort h, l2; bf16split(a9[j], h, l2);
                int c = e * 9 + j;
                if (c & 1) { rh[c >> 1] |= (unsigned)h << 16; rl[c >> 1] |= (unsigned)l2 << 16; }
                else       { rh[c >> 1] |= h;                  rl[c >> 1] |= l2; }
            }
        }
        ushort* oh = Oh + ((size_t)b * 256 + gpx) * 80 + cg * 18;
        ushort* ol = Ol + ((size_t)b * 256 + gpx) * 80 + cg * 18;
#pragma unroll
        for (int w = 0; w < 9; ++w) {
            *(unsigned*)(oh + w * 2) = rh[w];
            *(unsigned*)(ol + w * 2) = rl[w];
        }
        if (cg == 3) {
            ushort* ph2 = Oh + ((size_t)b * 256 + gpx) * 80 + 72;
            ushort* pl2 = Ol + ((size_t)b * 256 + gpx) * 80 + 72;
#pragma unroll
            for (int w = 0; w < 4; ++w) {
                *(unsigned*)(ph2 + w * 2) = 0u;
                *(unsigned*)(pl2 + w * 2) = 0u;
            }
        }
    }
}

// ---------------------------------------------------------------------------
// conv_mfma (unchanged, verified): 16x16 layers over padded-A LDS.
// ---------------------------------------------------------------------------
template <int NPH, int NCO, int POOL>
__global__ __launch_bounds__(256) void conv_mfma(
    const ushort* __restrict__ Agh, const ushort* __restrict__ Agl,
    const ushort* __restrict__ Bgh, const ushort* __restrict__ Bgl,
    const ushort* __restrict__ zph, const ushort* __restrict__ zpl,
    ushort* __restrict__ Oh, ushort* __restrict__ Ol,
    float* __restrict__ pooled) {
    __shared__ ushort AH[324 * AST];
    __shared__ ushort AL[324 * AST];
    const int tid = threadIdx.x;
    const int b = blockIdx.x;
    const int lane = tid & 63, wv = tid >> 6;

    f32x16 acc0, acc1;
#pragma unroll
    for (int i = 0; i < 16; ++i) { acc0[i] = 0.f; acc1[i] = 0.f; }

    const int r0 = wv * 64 + (lane & 31);
    const int r1 = r0 + 32;
    const int rp0 = ((r0 >> 4) + 1) * 18 + (r0 & 15) + 1;
    const int rp1 = ((r1 >> 4) + 1) * 18 + (r1 & 15) + 1;
    const int koff = (lane >> 5) * 8;

#pragma unroll 1
    for (int p = 0; p < NPH; ++p) {
        if (p) __syncthreads();
        const ushort* ash = Agh + ((size_t)b * NPH + p) * 256 * 80;
        const ushort* asl = Agl + ((size_t)b * NPH + p) * 256 * 80;
#pragma unroll
        for (int e = 0; e < 10; ++e) {
            int g4 = e * 256 + tid;
            int row = g4 / 10, ch = g4 - row * 10;
            int rp = ((row >> 4) + 1) * 18 + (row & 15) + 1;
            *(uint4*)(&AH[rp * AST + ch * 8]) = *(const uint4*)(ash + (size_t)g4 * 8);
            *(uint4*)(&AL[rp * AST + ch * 8]) = *(const uint4*)(asl + (size_t)g4 * 8);
        }
        for (int rr = tid; rr < 324; rr += 256) {
            int y = rr / 18, xx = rr - y * 18;
            if (y == 0 || y == 17 || xx == 0 || xx == 17) {
#pragma unroll
                for (int ch = 0; ch < 10; ++ch) {
                    *(uint4*)(&AH[rr * AST + ch * 8]) = *(const uint4*)(zph + ch * 8);
                    *(uint4*)(&AL[rr * AST + ch * 8]) = *(const uint4*)(zpl + ch * 8);
                }
            }
        }
        __syncthreads();

        const ushort* bsh = Bgh + (size_t)p * 2880 * 8;
        const ushort* bsl = Bgl + (size_t)p * 2880 * 8;
#pragma unroll 1
        for (int t = 0; t < 9; ++t) {
            const int dA = ((t / 3) - 1) * 18 + (t % 3) - 1;
#pragma unroll
            for (int s = 0; s < 5; ++s) {
                bf16x8 a0h = *(const bf16x8*)(&AH[(rp0 + dA) * AST + s * 16 + koff]);
                bf16x8 a0l = *(const bf16x8*)(&AL[(rp0 + dA) * AST + s * 16 + koff]);
                bf16x8 a1h = *(const bf16x8*)(&AH[(rp1 + dA) * AST + s * 16 + koff]);
                bf16x8 a1l = *(const bf16x8*)(&AL[(rp1 + dA) * AST + s * 16 + koff]);
                const ushort* bph = bsh + (size_t)((t * 5 + s) * 64 + lane) * 8;
                const ushort* bpl = bsl + (size_t)((t * 5 + s) * 64 + lane) * 8;
                bf16x8 bh = *(const bf16x8*)bph;
                bf16x8 bl = *(const bf16x8*)bpl;
                acc0 = __builtin_amdgcn_mfma_f32_32x32x16_bf16(a0h, bh, acc0, 0, 0, 0);
                acc1 = __builtin_amdgcn_mfma_f32_32x32x16_bf16(a1h, bh, acc1, 0, 0, 0);
                acc0 = __builtin_amdgcn_mfma_f32_32x32x16_bf16(a0h, bl, acc0, 0, 0, 0);
                acc1 = __builtin_amdgcn_mfma_f32_32x32x16_bf16(a1h, bl, acc1, 0, 0, 0);
                acc0 = __builtin_amdgcn_mfma_f32_32x32x16_bf16(a0l, bh, acc0, 0, 0, 0);
                acc1 = __builtin_amdgcn_mfma_f32_32x32x16_bf16(a1l, bh, acc1, 0, 0, 0);
            }
        }
    }
    __syncthreads();

    float* fl = (float*)AH;
    {
        int ccol = lane & 31;
        if (ccol < NCO) {
#pragma unroll
            for (int r = 0; r < 16; ++r) {
                int row = (r & 3) + 8 * (r >> 2) + 4 * (lane >> 5);
                fl[ccol * 257 + wv * 64 + row] = acc0[r];
                fl[ccol * 257 + wv * 64 + 32 + row] = acc1[r];
            }
        }
    }
    __syncthreads();

    if (POOL == 1) {
#pragma unroll
        for (int e = 0; e < NCO * 64 / 256; ++e) {
            int idx = e * 256 + tid;
            int co = idx >> 6, pp = idx & 63;
            int p2 = pp >> 3, w2 = pp & 7;
            const float* fb = fl + co * 257 + p2 * 32 + w2 * 2;
            float m = fmaxf(fmaxf(fb[0], fb[1]), fmaxf(fb[16], fb[17]));
            pooled[(size_t)b * (NCO * 64) + idx] = m;
        }
    } else {
        int px = tid;
#pragma unroll 1
        for (int p2 = 0; p2 < 2; ++p2) {
            unsigned rh[40], rl[40];
#pragma unroll
            for (int k = 0; k < 40; ++k) { rh[k] = 0u; rl[k] = 0u; }
#pragma unroll
            for (int co = 0; co < 8; ++co) {
                float v = fl[(p2 * 8 + co) * 257 + px];
                float a9[9];
                spline_acts(v, a9);
#pragma unroll
                for (int j = 0; j < 9; ++j) {
                    ushort h, l2; bf16split(a9[j], h, l2);
                    int c = co * 9 + j;
                    if (c & 1) { rh[c >> 1] |= (unsigned)h << 16; rl[c >> 1] |= (unsigned)l2 << 16; }
                    else       { rh[c >> 1] |= h;                  rl[c >> 1] |= l2; }
                }
            }
            ushort* oh = Oh + ((size_t)(b * 2 + p2) * 256 + px) * 80;
            ushort* ol = Ol + ((size_t)(b * 2 + p2) * 256 + px) * 80;
#pragma unroll
            for (int ch = 0; ch < 10; ++ch) {
                uint4 vh = {rh[ch * 4], rh[ch * 4 + 1], rh[ch * 4 + 2], rh[ch * 4 + 3]};
                uint4 vl = {rl[ch * 4], rl[ch * 4 + 1], rl[ch * 4 + 2], rl[ch * 4 + 3]};
                *(uint4*)(oh + ch * 8) = vh;
                *(uint4*)(ol + ch * 8) = vl;
            }
        }
    }
}

// ---------------------------------------------------------------------------
// fc_big: 64x64 tile, 4x4/thread, K_TILE=32, split-K via blockIdx.z.
// ---------------------------------------------------------------------------
template <int SPLIT>
__global__ __launch_bounds__(256) void fc_big(const float* __restrict__ A,
                                              const float* __restrict__ Wt,
                                              float* __restrict__ part,
                                              int M, int N, int K) {
    __shared__ float As[32][68];
    __shared__ float Ws[32][68];
    const int tid = threadIdx.x;
    const int tx = tid & 15, ty = tid >> 4;
    const int bm = blockIdx.y * 64, bn = blockIdx.x * 64;
    const int kc = K / SPLIT;
    const int kbeg = blockIdx.z * kc;
    float acc[4][4] = {};
    for (int k0 = kbeg; k0 < kbeg + kc; k0 += 32) {
#pragma unroll
        for (int e = 0; e < 8; ++e) {
            int g = e * 256 + tid;
            int k = g & 31, r = g >> 5;
            As[k][r] = A[(size_t)(bm + r) * K + k0 + k];
            Ws[k][r] = Wt[(size_t)(bn + r) * K + k0 + k];
        }
        __syncthreads();
#pragma unroll
        for (int kk = 0; kk < 32; ++kk) {
            float4 av = *(const float4*)(&As[kk][ty * 4]);
            float4 wv = *(const float4*)(&Ws[kk][tx * 4]);
            acc[0][0] = fmaf(av.x, wv.x, acc[0][0]);
            acc[0][1] = fmaf(av.x, wv.y, acc[0][1]);
            acc[0][2] = fmaf(av.x, wv.z, acc[0][2]);
            acc[0][3] = fmaf(av.x, wv.w, acc[0][3]);
            acc[1][0] = fmaf(av.y, wv.x, acc[1][0]);
            acc[1][1] = fmaf(av.y, wv.y, acc[1][1]);
            acc[1][2] = fmaf(av.y, wv.z, acc[1][2]);
            acc[1][3] = fmaf(av.y, wv.w, acc[1][3]);
            acc[2][0] = fmaf(av.z, wv.x, acc[2][0]);
            acc[2][1] = fmaf(av.z, wv.y, acc[2][1]);
            acc[2][2] = fmaf(av.z, wv.z, acc[2][2]);
            acc[2][3] = fmaf(av.z, wv.w, acc[2][3]);
            acc[3][0] = fmaf(av.w, wv.x, acc[3][0]);
            acc[3][1] = fmaf(av.w, wv.y, acc[3][1]);
            acc[3][2] = fmaf(av.w, wv.z, acc[3][2]);
            acc[3][3] = fmaf(av.w, wv.w, acc[3][3]);
        }
        __syncthreads();
    }
    float* p = part + (size_t)blockIdx.z * M * N;
#pragma unroll
    for (int i = 0; i < 4; ++i) {
        float4 v = make_float4(acc[i][0], acc[i][1], acc[i][2], acc[i][3]);
        *(float4*)&p[(size_t)(bm + ty * 4 + i) * N + (bn + tx * 4)] = v;
    }
}

template <int SPLIT>
__global__ void fc_reduce(const float* __restrict__ part, const float* __restrict__ bias,
                          float* __restrict__ C, int MN, int N, int relu) {
    int i = blockIdx.x * 256 + threadIdx.x;
    if (i >= MN) return;
    float s = bias[i % N];
#pragma unroll
    for (int z = 0; z < SPLIT; ++z) s += part[(size_t)z * MN + i];
    C[i] = relu ? fmaxf(s, 0.f) : s;
}

__global__ __launch_bounds__(256) void fc3_kernel(const float* __restrict__ A,
                                                  const float* __restrict__ Wt,
                                                  const float* __restrict__ bias,
                                                  float* __restrict__ C) {
    int gid = blockIdx.x * 256 + threadIdx.x;
    int wid = gid >> 6;
    int lane = gid & 63;
    int m = wid / 10, n = wid - m * 10;
    const float4* a = (const float4*)(A + (size_t)m * 1024);
    const float4* w = (const float4*)(Wt + (size_t)n * 1024);
    float s = 0.f;
#pragma unroll
    for (int it = 0; it < 4; ++it) {
        float4 av = a[it * 64 + lane];
        float4 wv = w[it * 64 + lane];
        s += av.x * wv.x + av.y * wv.y + av.z * wv.z + av.w * wv.w;
    }
#pragma unroll
    for (int off = 32; off; off >>= 1) s += __shfl_xor(s, off);
    if (lane == 0) C[wid] = s + bias[n];
}

// ---------------------------------------------------------------------------
extern "C" void kernel_launch(void* const* d_in, const int* in_sizes, int n_in,
                              void* d_out, int out_size, void* d_ws, size_t ws_size,
                              hipStream_t stream) {
    const float* x   = (const float*)d_in[0];
    const float* bw1 = (const float*)d_in[1];
    const float* sw1 = (const float*)d_in[2];
    const float* sc1 = (const float*)d_in[3];
    const float* bw2 = (const float*)d_in[4];
    const float* sw2 = (const float*)d_in[5];
    const float* sc2 = (const float*)d_in[6];
    const float* bw3 = (const float*)d_in[7];
    const float* sw3 = (const float*)d_in[8];
    const float* sc3 = (const float*)d_in[9];
    const float* bw4 = (const float*)d_in[10];
    const float* sw4 = (const float*)d_in[11];
    const float* sc4 = (const float*)d_in[12];
    const float* w1  = (const float*)d_in[13];
    const float* b1  = (const float*)d_in[14];
    const float* w2  = (const float*)d_in[15];
    const float* b2  = (const float*)d_in[16];
    const float* w3  = (const float*)d_in[17];
    const float* b3  = (const float*)d_in[18];

    float*  wsf = (float*)d_ws;
    ushort* wsu = (ushort*)d_ws;
    float* wp1 = wsf;            // fp32 packed weights [0, 55404) floats
    float* wp2 = wsf + 972;
    float* wp3 = wsf + 3564;
    float* wp4 = wsf + 13932;
    // bf16 frag arrays (ushort offsets)
    ushort* k1h = wsu + 110848;  // 9216
    ushort* k1l = wsu + 120064;
    ushort* k2h = wsu + 129280;  // 13824
    ushort* k2l = wsu + 143104;
    ushort* k3h = wsu + 156928;  // 23040
    ushort* k3l = wsu + 179968;
    ushort* k4h = wsu + 203008;  // 46080
    ushort* k4l = wsu + 249088;
    ushort* zph = wsu + 295168;  // 80
    ushort* zpl = wsu + 295248;
    // activations (ushort offsets from wsu, byte = 2x):
    ushort* A1h = wsu + 524288;     // byte [1.0M, 8.3M)   (B,1024,28)
    ushort* A1l = wsu + 4194304;    // byte [8.4M, 15.7M)
    ushort* A2h = wsu + 7864320;    // byte [15.7M, 25.2M) (B,1024,36)
    ushort* A2l = wsu + 12582912;   // byte [25.2M, 34.6M)
    ushort* A3h = wsu + 524288;     // byte [1.0M, 6.3M)   (B,256,80)  over dead A1
    ushort* A3l = wsu + 3145728;    // byte [6.3M, 11.5M)
    ushort* A4h = wsu + 5767168;    // byte [11.5M, 22.0M) (B,2,256,80)
    ushort* A4l = wsu + 11010048;   // byte [22.0M, 32.5M) over dead A2
    float* pooled = wsf + 262144;   // byte [1.0M, 2.0M)   over dead A3
    float* part1  = wsf + 524288;   // byte [2.0M, 10.4M)  8x(128,2048)
    float* fc1o   = wsf + 2621440;  // byte [10.4M, 11.5M)
    float* part2  = wsf + 2883584;  // byte [11.5M, 15.5M) 8x(128,1024) over dead A4
    float* fc2o   = wsf + 3932160;  // byte [15.7M, 16.3M)
    // peak ws use ~34.6 MB

    pack_all<<<(55404 + 255) / 256, 256, 0, stream>>>(bw1, sw1, sc1, bw2, sw2, sc2,
                                                      bw3, sw3, sc3, bw4, sw4, sc4, wsf);
    pack_frags<<<46, 256, 0, stream>>>(wp1, wp2, wp3, wp4, k1h, k1l, k2h, k2l,
                                       k3h, k3l, k4h, k4l, zph, zpl);

    // spline of input: x -> A1
    spline_x<<<512, 256, 0, stream>>>(x, A1h, A1l);
    // conv1 strip-MFMA + spline -> A2
    conv_strip<28, 7, 8, 40, 2, 4, 0><<<512, 256, 0, stream>>>(A1h, A1l, k1h, k1l,
                                                               zph, zpl, A2h, A2l);
    // conv2 strip-MFMA + pool + spline -> A3
    conv_strip<36, 9, 12, 56, 3, 8, 1><<<512, 256, 0, stream>>>(A2h, A2l, k2h, k2l,
                                                                zph, zpl, A3h, A3l);
    // conv3 MFMA + spline -> A4
    conv_mfma<1, 16, 0><<<128, 256, 0, stream>>>(A3h, A3l, k3h, k3l, zph, zpl,
                                                 A4h, A4l, nullptr);
    // conv4 MFMA + pool -> pooled (B,2048)
    conv_mfma<2, 32, 1><<<128, 256, 0, stream>>>(A4h, A4l, k4h, k4l, zph, zpl,
                                                 nullptr, nullptr, pooled);
    // fc1: relu(pooled @ w1.T + b1), split-K=8
    fc_big<8><<<dim3(32, 2, 8), 256, 0, stream>>>(pooled, w1, part1, 128, 2048, 2048);
    fc_reduce<8><<<1024, 256, 0, stream>>>(part1, b1, fc1o, 262144, 2048, 1);
    // fc2: relu(fc1o @ w2.T + b2), split-K=8
    fc_big<8><<<dim3(16, 2, 8), 256, 0, stream>>>(fc1o, w2, part2, 128, 1024, 2048);
    fc_reduce<8><<<512, 256, 0, stream>>>(part2, b2, fc2o, 131072, 1024, 1);
    // fc3
    fc3_kernel<<<320, 256, 0, stream>>>(fc2o, w3, b3, (float*)d_out);
}

// Round 10
// 157.099 us; speedup vs baseline: 4.4115x; 1.1114x over previous
//
#include <hip/hip_runtime.h>

#define BATCH 128
#define AST 88  // padded-A LDS row stride in ushorts (176B, 16B-aligned)

typedef __attribute__((ext_vector_type(8))) short bf16x8;
typedef __attribute__((ext_vector_type(16))) float f32x16;

// ---------------------------------------------------------------------------
// Spline activation: act[0] = silu(x), act[1..8] = cubic B-spline bases
// ---------------------------------------------------------------------------
__device__ __forceinline__ void spline_acts(float xv, float act[9]) {
    act[0] = xv * (1.0f / (1.0f + __expf(-xv)));  // silu
    float g[12];
#pragma unroll
    for (int i = 0; i < 12; ++i) g[i] = (float)(i - 3) * 0.4f - 1.0f;
    float bb[11];
#pragma unroll
    for (int c = 0; c < 11; ++c) bb[c] = (xv >= g[c] && xv < g[c + 1]) ? 1.0f : 0.0f;
#pragma unroll
    for (int k = 1; k <= 3; ++k) {
#pragma unroll
        for (int c = 0; c + k < 11; ++c) {
            float left  = (xv - g[c]) * (1.0f / (g[c + k] - g[c])) * bb[c];
            float right = (g[c + k + 1] - xv) * (1.0f / (g[c + k + 1] - g[c + 1])) * bb[c + 1];
            bb[c] = left + right;
        }
    }
#pragma unroll
    for (int c = 0; c < 8; ++c) act[c + 1] = bb[c];
}

__device__ __constant__ float ZPAD[9] = {0.0f, 0.0f, 0.0f, 0.02083333333f,
                                         0.47916666667f, 0.47916666667f,
                                         0.02083333333f, 0.0f, 0.0f};

// bf16 hi/lo split (round-to-nearest-even); x = hi + lo + O(2^-18 x)
__device__ __forceinline__ void bf16split(float x, ushort& h, ushort& l) {
    union { float f; unsigned u; } a; a.f = x;
    unsigned r = a.u + 0x7FFF + ((a.u >> 16) & 1);
    h = (ushort)(r >> 16);
    union { unsigned u; float f; } hf; hf.u = (unsigned)h << 16;
    union { float f; unsigned u; } bres; bres.f = x - hf.f;
    unsigned r2 = bres.u + 0x7FFF + ((bres.u >> 16) & 1);
    l = (ushort)(r2 >> 16);
}

// ---------------------------------------------------------------------------
// Pack weights (fp32): wpack[(cin*9+tap)*9*O + j*O + o] = j==0 ? bw : sw*sc
// ---------------------------------------------------------------------------
__device__ __forceinline__ void pack_one(int i, const float* bw, const float* sw,
                                         const float* sc, float* out, int F, int O) {
    int o = i % O;
    int j = (i / O) % 9;
    int f = i / (9 * O);
    float v;
    if (j == 0) v = bw[o * F + f];
    else        v = sw[(o * F + f) * 8 + (j - 1)] * sc[o * F + f];
    out[i] = v;
}

__global__ void pack_all(const float* __restrict__ bw1, const float* __restrict__ sw1,
                         const float* __restrict__ sc1, const float* __restrict__ bw2,
                         const float* __restrict__ sw2, const float* __restrict__ sc2,
                         const float* __restrict__ bw3, const float* __restrict__ sw3,
                         const float* __restrict__ sc3, const float* __restrict__ bw4,
                         const float* __restrict__ sw4, const float* __restrict__ sc4,
                         float* __restrict__ ws) {
    int i = blockIdx.x * blockDim.x + threadIdx.x;
    if (i < 972)        pack_one(i,         bw1, sw1, sc1, ws,         27, 4);
    else if (i < 3564)  pack_one(i - 972,   bw2, sw2, sc2, ws + 972,   36, 8);
    else if (i < 13932) pack_one(i - 3564,  bw3, sw3, sc3, ws + 3564,  72, 16);
    else if (i < 55404) pack_one(i - 13932, bw4, sw4, sc4, ws + 13932, 144, 32);
}

// ---------------------------------------------------------------------------
// Pack MFMA B-fragments (bf16 hi/lo) for all 4 conv layers + zp pattern.
// B-frag (32x32x16): value(lane l, elem e) = W[k = s*16+(l>>5)*8+e][o = l&31]
// ---------------------------------------------------------------------------
__global__ void pack_frags(const float* __restrict__ wp1, const float* __restrict__ wp2,
                           const float* __restrict__ wp3, const float* __restrict__ wp4,
                           ushort* __restrict__ k1h, ushort* __restrict__ k1l,
                           ushort* __restrict__ k2h, ushort* __restrict__ k2l,
                           ushort* __restrict__ k3h, ushort* __restrict__ k3l,
                           ushort* __restrict__ k4h, ushort* __restrict__ k4l,
                           ushort* __restrict__ zph, ushort* __restrict__ zpl) {
    int i = blockIdx.x * 256 + threadIdx.x;
    if (i < 1152) {                            // conv1: (t, 2 ksteps, l)
        int l = i & 63, s = (i >> 6) & 1, t = i / 128;
#pragma unroll
        for (int e = 0; e < 8; ++e) {
            int k = s * 16 + ((l >> 5) * 8) + e, o = l & 31;
            float w = 0.f;
            if (k < 27 && o < 4) w = wp1[(((k / 9) * 9 + t) * 9 + (k % 9)) * 4 + o];
            ushort h, lo; bf16split(w, h, lo);
            k1h[i * 8 + e] = h; k1l[i * 8 + e] = lo;
        }
    } else if (i < 2880) {                     // conv2: (t, 3 ksteps, l)
        int q = i - 1152;
        int l = q & 63, s = (q >> 6) % 3, t = q / 192;
#pragma unroll
        for (int e = 0; e < 8; ++e) {
            int k = s * 16 + ((l >> 5) * 8) + e, o = l & 31;
            float w = 0.f;
            if (k < 36 && o < 8) w = wp2[(((k / 9) * 9 + t) * 9 + (k % 9)) * 8 + o];
            ushort h, lo; bf16split(w, h, lo);
            k2h[q * 8 + e] = h; k2l[q * 8 + e] = lo;
        }
    } else if (i < 5760) {                     // conv3: (t, 5 ksteps, l)
        int q = i - 2880;
        int l = q & 63, s = (q >> 6) % 5, t = q / 320;
#pragma unroll
        for (int e = 0; e < 8; ++e) {
            int k = s * 16 + ((l >> 5) * 8) + e, o = l & 31;
            float w = 0.f;
            if (k < 72 && o < 16) w = wp3[(((k / 9) * 9 + t) * 9 + (k % 9)) * 16 + o];
            ushort h, lo; bf16split(w, h, lo);
            k3h[q * 8 + e] = h; k3l[q * 8 + e] = lo;
        }
    } else if (i < 11520) {                    // conv4: (phase, t, 5 ksteps, l)
        int q = i - 5760;
        int l = q & 63, s = (q >> 6) % 5, t = (q / 320) % 9, p = q / 2880;
#pragma unroll
        for (int e = 0; e < 8; ++e) {
            int k = s * 16 + ((l >> 5) * 8) + e, o = l & 31;
            float w = 0.f;
            if (k < 72) w = wp4[(((p * 8 + k / 9) * 9 + t) * 9 + (k % 9)) * 32 + o];
            ushort h, lo; bf16split(w, h, lo);
            k4h[q * 8 + e] = h; k4l[q * 8 + e] = lo;
        }
    } else if (i < 11600) {
        int c = i - 11520;
        ushort h, lo; bf16split(ZPAD[c % 9], h, lo);
        zph[c] = h; zpl[c] = lo;
    }
}

// ---------------------------------------------------------------------------
// spline_x: raw x (B,3,32,32) -> A1 (B,1024,28) bf16 hi/lo, coalesced via LDS
// ---------------------------------------------------------------------------
__global__ __launch_bounds__(256) void spline_x(const float* __restrict__ x,
                                                ushort* __restrict__ A1h,
                                                ushort* __restrict__ A1l) {
    __shared__ unsigned SB[7168];  // hi words [0,3584), lo words [3584,7168)
    int i = blockIdx.x * 256 + threadIdx.x;
    int px = i & 1023, b = i >> 10;
    const float* xb = x + (size_t)b * 3072 + px;
    unsigned rh[14] = {}, rl[14] = {};
#pragma unroll
    for (int cin = 0; cin < 3; ++cin) {
        float a9[9];
        spline_acts(xb[cin * 1024], a9);
#pragma unroll
        for (int j = 0; j < 9; ++j) {
            ushort h, l2; bf16split(a9[j], h, l2);
            int c = cin * 9 + j;
            if (c & 1) { rh[c >> 1] |= (unsigned)h << 16; rl[c >> 1] |= (unsigned)l2 << 16; }
            else       { rh[c >> 1] |= h;                  rl[c >> 1] |= l2; }
        }
    }
    int wb = threadIdx.x * 14;
#pragma unroll
    for (int w = 0; w < 14; ++w) { SB[wb + w] = rh[w]; SB[3584 + wb + w] = rl[w]; }
    __syncthreads();
    const ushort* sb = (const ushort*)SB;
    size_t base = (size_t)blockIdx.x * 7168;
    // 256 px * 28 ushorts = 7168 ushorts = 896 uint4 per buffer (FIX: was 448)
#pragma unroll
    for (int e = 0; e < 4; ++e) {
        int q = e * 256 + threadIdx.x;
        if (q < 896) {
            *(uint4*)(A1h + base + q * 8) = *(const uint4*)(sb + q * 8);
            *(uint4*)(A1l + base + q * 8) = *(const uint4*)(sb + 7168 + q * 8);
        }
    }
}

// ---------------------------------------------------------------------------
// Strip MFMA conv for 32x32 layers. Block = one 8-row strip of one image.
// EPI=0: spline -> A2 (36 cols). EPI=1: pool + spline -> A3 (80 cols).
// Epilogue writes go through a dense LDS bounce -> coalesced copy-out.
// ---------------------------------------------------------------------------
template <int KG, int CHG, int CHL, int ASTR, int KSTEPS, int NCO, int EPI>
__global__ __launch_bounds__(256) void conv_strip(
    const ushort* __restrict__ Agh, const ushort* __restrict__ Agl,
    const ushort* __restrict__ Bgh, const ushort* __restrict__ Bgl,
    const ushort* __restrict__ zph, const ushort* __restrict__ zpl,
    ushort* __restrict__ Oh, ushort* __restrict__ Ol) {
    __shared__ ushort AH[340 * ASTR];
    __shared__ ushort AL[340 * ASTR];
    const int tid = threadIdx.x;
    const int b = blockIdx.x >> 2, strip = blockIdx.x & 3;
    const int r0 = strip * 8;
    const int lane = tid & 63, wv = tid >> 6;

    {
        const ushort* ash = Agh + (size_t)b * 1024 * KG;
        const ushort* asl = Agl + (size_t)b * 1024 * KG;
        for (int idx = tid; idx < 320 * CHL; idx += 256) {
            int pxl = idx / CHL, ch = idx - pxl * CHL;
            int lr = pxl >> 5, c = pxl & 31;
            int grow = r0 - 1 + lr;
            uint2 vh, vl;
            if (ch >= CHG) { vh = make_uint2(0u, 0u); vl = make_uint2(0u, 0u); }
            else if ((unsigned)grow < 32u) {
                vh = *(const uint2*)(ash + (size_t)(grow * 32 + c) * KG + ch * 4);
                vl = *(const uint2*)(asl + (size_t)(grow * 32 + c) * KG + ch * 4);
            } else {
                vh = *(const uint2*)(zph + ch * 4);
                vl = *(const uint2*)(zpl + ch * 4);
            }
            int spx = lr * 34 + c + 1;
            *(uint2*)(&AH[spx * ASTR + ch * 4]) = vh;
            *(uint2*)(&AL[spx * ASTR + ch * 4]) = vl;
        }
        for (int idx = tid; idx < 20 * CHL; idx += 256) {
            int sel = idx / CHL, ch = idx - sel * CHL;
            int lr = sel >> 1, c = (sel & 1) ? 33 : 0;
            int spx = lr * 34 + c;
            uint2 vh, vl;
            if (ch >= CHG) { vh = make_uint2(0u, 0u); vl = make_uint2(0u, 0u); }
            else { vh = *(const uint2*)(zph + ch * 4); vl = *(const uint2*)(zpl + ch * 4); }
            *(uint2*)(&AH[spx * ASTR + ch * 4]) = vh;
            *(uint2*)(&AL[spx * ASTR + ch * 4]) = vl;
        }
    }
    __syncthreads();

    f32x16 acc0, acc1;
#pragma unroll
    for (int i = 0; i < 16; ++i) { acc0[i] = 0.f; acc1[i] = 0.f; }

    const int p0 = wv * 64 + (lane & 31);
    const int sp0 = ((p0 >> 5) + 1) * 34 + (p0 & 31) + 1;
    const int sp1 = sp0 + 34;
    const int koff = (lane >> 5) * 8;

#pragma unroll 1
    for (int t = 0; t < 9; ++t) {
        const int dA = ((t / 3) - 1) * 34 + (t % 3) - 1;
#pragma unroll
        for (int s = 0; s < KSTEPS; ++s) {
            bf16x8 a0h = *(const bf16x8*)(&AH[(sp0 + dA) * ASTR + s * 16 + koff]);
            bf16x8 a0l = *(const bf16x8*)(&AL[(sp0 + dA) * ASTR + s * 16 + koff]);
            bf16x8 a1h = *(const bf16x8*)(&AH[(sp1 + dA) * ASTR + s * 16 + koff]);
            bf16x8 a1l = *(const bf16x8*)(&AL[(sp1 + dA) * ASTR + s * 16 + koff]);
            bf16x8 bh = *(const bf16x8*)(Bgh + (size_t)((t * KSTEPS + s) * 64 + lane) * 8);
            bf16x8 bl = *(const bf16x8*)(Bgl + (size_t)((t * KSTEPS + s) * 64 + lane) * 8);
            acc0 = __builtin_amdgcn_mfma_f32_32x32x16_bf16(a0h, bh, acc0, 0, 0, 0);
            acc1 = __builtin_amdgcn_mfma_f32_32x32x16_bf16(a1h, bh, acc1, 0, 0, 0);
            acc0 = __builtin_amdgcn_mfma_f32_32x32x16_bf16(a0h, bl, acc0, 0, 0, 0);
            acc1 = __builtin_amdgcn_mfma_f32_32x32x16_bf16(a1h, bl, acc1, 0, 0, 0);
            acc0 = __builtin_amdgcn_mfma_f32_32x32x16_bf16(a0l, bh, acc0, 0, 0, 0);
            acc1 = __builtin_amdgcn_mfma_f32_32x32x16_bf16(a1l, bh, acc1, 0, 0, 0);
        }
    }
    __syncthreads();

    // transpose acc -> LDS fp32 [NCO][257] at the start of AH
    float* fl = (float*)AH;
    {
        int ccol = lane & 31;
        if (ccol < NCO) {
#pragma unroll
            for (int r = 0; r < 16; ++r) {
                int row = (r & 3) + 8 * (r >> 2) + 4 * (lane >> 5);
                fl[ccol * 257 + wv * 64 + row] = acc0[r];
                fl[ccol * 257 + wv * 64 + 32 + row] = acc1[r];
            }
        }
    }
    __syncthreads();

    if (EPI == 0) {
        // conv1: spline -> dense 18-word rows (36 ushorts), then word memcpy
        unsigned* ubh = (unsigned*)AL;                 // 4608 words
        unsigned* ubl = (unsigned*)AH + 1032;          // fl = 1028 words
        unsigned rwh[18], rwl[18];
#pragma unroll
        for (int w = 0; w < 18; ++w) { rwh[w] = 0u; rwl[w] = 0u; }
#pragma unroll
        for (int co = 0; co < 4; ++co) {
            float a9[9];
            spline_acts(fl[co * 257 + tid], a9);
#pragma unroll
            for (int j = 0; j < 9; ++j) {
                ushort h, l2; bf16split(a9[j], h, l2);
                int c = co * 9 + j;
                if (c & 1) { rwh[c >> 1] |= (unsigned)h << 16; rwl[c >> 1] |= (unsigned)l2 << 16; }
                else       { rwh[c >> 1] |= h;                  rwl[c >> 1] |= l2; }
            }
        }
#pragma unroll
        for (int w = 0; w < 18; ++w) { ubh[tid * 18 + w] = rwh[w]; ubl[tid * 18 + w] = rwl[w]; }
        __syncthreads();
        size_t basew = ((size_t)b * 1024 + strip * 256) * 18;
        unsigned* goh = (unsigned*)Oh + basew;
        unsigned* gol = (unsigned*)Ol + basew;
#pragma unroll
        for (int e = 0; e < 18; ++e) {
            int q = e * 256 + tid;
            goh[q] = ubh[q];
            gol[q] = ubl[q];
        }
    } else {
        // conv2: pool + spline -> dense 80-ushort rows, then uint4 memcpy
        int cg = tid >> 6, pl = tid & 63;
        int phl = pl >> 4, pw = pl & 15;
        int base_m = (2 * phl) * 32 + 2 * pw;
        unsigned rwh[9], rwl[9];
#pragma unroll
        for (int w = 0; w < 9; ++w) { rwh[w] = 0u; rwl[w] = 0u; }
#pragma unroll
        for (int e = 0; e < 2; ++e) {
            int co = cg * 2 + e;
            const float* fb = fl + co * 257 + base_m;
            float m = fmaxf(fmaxf(fb[0], fb[1]), fmaxf(fb[32], fb[33]));
            float a9[9];
            spline_acts(m, a9);
#pragma unroll
            for (int j = 0; j < 9; ++j) {
                ushort h, l2; bf16split(a9[j], h, l2);
                int c = e * 9 + j;
                if (c & 1) { rwh[c >> 1] |= (unsigned)h << 16; rwl[c >> 1] |= (unsigned)l2 << 16; }
                else       { rwh[c >> 1] |= h;                  rwl[c >> 1] |= l2; }
            }
        }
        unsigned* ubh = (unsigned*)AL;          // 2560 words
        unsigned* ubl = (unsigned*)AL + 2560;   // 2560 words
#pragma unroll
        for (int w = 0; w < 9; ++w) {
            ubh[pl * 40 + cg * 9 + w] = rwh[w];
            ubl[pl * 40 + cg * 9 + w] = rwl[w];
        }
        if (cg == 3) {
#pragma unroll
            for (int w = 0; w < 4; ++w) { ubh[pl * 40 + 36 + w] = 0u; ubl[pl * 40 + 36 + w] = 0u; }
        }
        __syncthreads();
        size_t base = ((size_t)b * 256 + strip * 64) * 80;
        const ushort* sbh = (const ushort*)ubh;
        const ushort* sbl = (const ushort*)ubl;
        // 64 px * 80 ushorts = 5120 ushorts = 640 uint4 per buffer (FIX: was 320)
#pragma unroll
        for (int e = 0; e < 3; ++e) {
            int q = e * 256 + tid;
            if (q < 640) {
                *(uint4*)(Oh + base + q * 8) = *(const uint4*)(sbh + q * 8);
                *(uint4*)(Ol + base + q * 8) = *(const uint4*)(sbl + q * 8);
            }
        }
    }
}

// ---------------------------------------------------------------------------
// conv34: half-image MFMA conv for 16x16 layers. Block = 8 rows (128 px) of
// one image; LDS 63KB -> 2 blocks/CU. A: (B,NPH,256,80) bf16 hi/lo.
// POOL=0: spline -> A4 via dense LDS bounce. POOL=1: 2x2 pool -> pooled fp32.
// ---------------------------------------------------------------------------
template <int NPH, int NCO, int POOL>
__global__ __launch_bounds__(256) void conv34(
    const ushort* __restrict__ Agh, const ushort* __restrict__ Agl,
    const ushort* __restrict__ Bgh, const ushort* __restrict__ Bgl,
    const ushort* __restrict__ zph, const ushort* __restrict__ zpl,
    ushort* __restrict__ Oh, ushort* __restrict__ Ol,
    float* __restrict__ pooled) {
    __shared__ ushort AH[180 * AST];  // 31680 B
    __shared__ ushort AL[180 * AST];
    const int tid = threadIdx.x;
    const int b = blockIdx.x;
    const int half = blockIdx.y;
    const int r0 = half * 8;
    const int lane = tid & 63, wv = tid >> 6;

    f32x16 acc;
#pragma unroll
    for (int i = 0; i < 16; ++i) acc[i] = 0.f;

    const int m = wv * 32 + (lane & 31);              // local px 0..127
    const int spx = ((m >> 4) + 1) * 18 + (m & 15) + 1;
    const int koff = (lane >> 5) * 8;

#pragma unroll 1
    for (int p = 0; p < NPH; ++p) {
        if (p) __syncthreads();
        const ushort* ash = Agh + ((size_t)b * NPH + p) * 256 * 80;
        const ushort* asl = Agl + ((size_t)b * NPH + p) * 256 * 80;
#pragma unroll
        for (int e = 0; e < 8; ++e) {
            int idx = e * 256 + tid;
            if (idx < 1800) {
                int px = idx / 10, ch = idx - px * 10;
                int pr = px / 18, pc = px - pr * 18;
                int r = r0 - 1 + pr, c = pc - 1;
                bool inb = ((unsigned)r < 16u) && ((unsigned)c < 16u);
                uint4 vh, vl;
                if (inb) {
                    vh = *(const uint4*)(ash + (size_t)(r * 16 + c) * 80 + ch * 8);
                    vl = *(const uint4*)(asl + (size_t)(r * 16 + c) * 80 + ch * 8);
                } else {
                    vh = *(const uint4*)(zph + ch * 8);
                    vl = *(const uint4*)(zpl + ch * 8);
                }
                *(uint4*)(&AH[px * AST + ch * 8]) = vh;
                *(uint4*)(&AL[px * AST + ch * 8]) = vl;
            }
        }
        __syncthreads();

        const ushort* bsh = Bgh + (size_t)p * 2880 * 8;
        const ushort* bsl = Bgl + (size_t)p * 2880 * 8;
#pragma unroll 1
        for (int t = 0; t < 9; ++t) {
            const int dA = ((t / 3) - 1) * 18 + (t % 3) - 1;
#pragma unroll
            for (int s = 0; s < 5; ++s) {
                bf16x8 ah = *(const bf16x8*)(&AH[(spx + dA) * AST + s * 16 + koff]);
                bf16x8 al = *(const bf16x8*)(&AL[(spx + dA) * AST + s * 16 + koff]);
                bf16x8 bh = *(const bf16x8*)(bsh + (size_t)((t * 5 + s) * 64 + lane) * 8);
                bf16x8 bl = *(const bf16x8*)(bsl + (size_t)((t * 5 + s) * 64 + lane) * 8);
                acc = __builtin_amdgcn_mfma_f32_32x32x16_bf16(ah, bh, acc, 0, 0, 0);
                acc = __builtin_amdgcn_mfma_f32_32x32x16_bf16(ah, bl, acc, 0, 0, 0);
                acc = __builtin_amdgcn_mfma_f32_32x32x16_bf16(al, bh, acc, 0, 0, 0);
            }
        }
    }
    __syncthreads();

    // transpose acc -> fl [NCO][129] at start of AH
    float* fl = (float*)AH;
    {
        int ccol = lane & 31;
        if (ccol < NCO) {
#pragma unroll
            for (int r = 0; r < 16; ++r) {
                int row = (r & 3) + 8 * (r >> 2) + 4 * (lane >> 5);
                fl[ccol * 129 + wv * 32 + row] = acc[r];
            }
        }
    }
    __syncthreads();

    if (POOL == 1) {
        // 2x2 pool over this half's 8 rows -> 4 pooled rows x 8 cols x NCO
#pragma unroll
        for (int e = 0; e < NCO * 32 / 256; ++e) {
            int idx = e * 256 + tid;
            int co = idx >> 5, pp = idx & 31;
            int prl = pp >> 3, pc = pp & 7;
            int mbase = (2 * prl) * 16 + 2 * pc;
            const float* fb = fl + co * 129 + mbase;
            float v = fmaxf(fmaxf(fb[0], fb[1]), fmaxf(fb[16], fb[17]));
            pooled[(size_t)b * 2048 + co * 64 + (r0 / 2 + prl) * 8 + pc] = v;
        }
    } else {
        // spline epilogue -> A4 via dense bounce (80-ushort rows), per phase
        unsigned* ubh = (unsigned*)AL;            // 5120 words
        unsigned* ubl = (unsigned*)AH + 2064;     // after fl (2064 words)
#pragma unroll 1
        for (int p2 = 0; p2 < 2; ++p2) {
            if (p2) __syncthreads();
            int px = tid & 127, cohalf = tid >> 7;
            unsigned rwh[18], rwl[18];
#pragma unroll
            for (int w = 0; w < 18; ++w) { rwh[w] = 0u; rwl[w] = 0u; }
#pragma unroll
            for (int e = 0; e < 4; ++e) {
                float v = fl[(p2 * 8 + cohalf * 4 + e) * 129 + px];
                float a9[9];
                spline_acts(v, a9);
#pragma unroll
                for (int j = 0; j < 9; ++j) {
                    ushort h, l2; bf16split(a9[j], h, l2);
                    int c = e * 9 + j;
                    if (c & 1) { rwh[c >> 1] |= (unsigned)h << 16; rwl[c >> 1] |= (unsigned)l2 << 16; }
                    else       { rwh[c >> 1] |= h;                  rwl[c >> 1] |= l2; }
                }
            }
            int wb = px * 40 + cohalf * 18;
#pragma unroll
            for (int w = 0; w < 18; ++w) { ubh[wb + w] = rwh[w]; ubl[wb + w] = rwl[w]; }
            if (cohalf) {
#pragma unroll
                for (int w = 0; w < 4; ++w) { ubh[px * 40 + 36 + w] = 0u; ubl[px * 40 + 36 + w] = 0u; }
            }
            __syncthreads();
            const ushort* sbh = (const ushort*)ubh;
            const ushort* sbl = (const ushort*)ubl;
            size_t base = ((size_t)(b * 2 + p2) * 256 + r0 * 16) * 80;
            // 128 px * 80 ushorts = 10240 ushorts = 1280 uint4 (FIX: was 640)
#pragma unroll
            for (int e = 0; e < 5; ++e) {
                int q = e * 256 + tid;
                if (q < 1280) {
                    *(uint4*)(Oh + base + q * 8) = *(const uint4*)(sbh + q * 8);
                    *(uint4*)(Ol + base + q * 8) = *(const uint4*)(sbl + q * 8);
                }
            }
        }
    }
}

// ---------------------------------------------------------------------------
// fc_big: 64x64 tile, 4x4/thread, K_TILE=32, split-K via blockIdx.z.
// ---------------------------------------------------------------------------
template <int SPLIT>
__global__ __launch_bounds__(256) void fc_big(const float* __restrict__ A,
                                              const float* __restrict__ Wt,
                                              float* __restrict__ part,
                                              int M, int N, int K) {
    __shared__ float As[32][68];
    __shared__ float Ws[32][68];
    const int tid = threadIdx.x;
    const int tx = tid & 15, ty = tid >> 4;
    const int bm = blockIdx.y * 64, bn = blockIdx.x * 64;
    const int kc = K / SPLIT;
    const int kbeg = blockIdx.z * kc;
    float acc[4][4] = {};
    for (int k0 = kbeg; k0 < kbeg + kc; k0 += 32) {
#pragma unroll
        for (int e = 0; e < 8; ++e) {
            int g = e * 256 + tid;
            int k = g & 31, r = g >> 5;
            As[k][r] = A[(size_t)(bm + r) * K + k0 + k];
            Ws[k][r] = Wt[(size_t)(bn + r) * K + k0 + k];
        }
        __syncthreads();
#pragma unroll
        for (int kk = 0; kk < 32; ++kk) {
            float4 av = *(const float4*)(&As[kk][ty * 4]);
            float4 wv = *(const float4*)(&Ws[kk][tx * 4]);
            acc[0][0] = fmaf(av.x, wv.x, acc[0][0]);
            acc[0][1] = fmaf(av.x, wv.y, acc[0][1]);
            acc[0][2] = fmaf(av.x, wv.z, acc[0][2]);
            acc[0][3] = fmaf(av.x, wv.w, acc[0][3]);
            acc[1][0] = fmaf(av.y, wv.x, acc[1][0]);
            acc[1][1] = fmaf(av.y, wv.y, acc[1][1]);
            acc[1][2] = fmaf(av.y, wv.z, acc[1][2]);
            acc[1][3] = fmaf(av.y, wv.w, acc[1][3]);
            acc[2][0] = fmaf(av.z, wv.x, acc[2][0]);
            acc[2][1] = fmaf(av.z, wv.y, acc[2][1]);
            acc[2][2] = fmaf(av.z, wv.z, acc[2][2]);
            acc[2][3] = fmaf(av.z, wv.w, acc[2][3]);
            acc[3][0] = fmaf(av.w, wv.x, acc[3][0]);
            acc[3][1] = fmaf(av.w, wv.y, acc[3][1]);
            acc[3][2] = fmaf(av.w, wv.z, acc[3][2]);
            acc[3][3] = fmaf(av.w, wv.w, acc[3][3]);
        }
        __syncthreads();
    }
    float* p = part + (size_t)blockIdx.z * M * N;
#pragma unroll
    for (int i = 0; i < 4; ++i) {
        float4 v = make_float4(acc[i][0], acc[i][1], acc[i][2], acc[i][3]);
        *(float4*)&p[(size_t)(bm + ty * 4 + i) * N + (bn + tx * 4)] = v;
    }
}

template <int SPLIT>
__global__ void fc_reduce(const float* __restrict__ part, const float* __restrict__ bias,
                          float* __restrict__ C, int MN, int N, int relu) {
    int i = blockIdx.x * 256 + threadIdx.x;
    if (i >= MN) return;
    float s = bias[i % N];
#pragma unroll
    for (int z = 0; z < SPLIT; ++z) s += part[(size_t)z * MN + i];
    C[i] = relu ? fmaxf(s, 0.f) : s;
}

__global__ __launch_bounds__(256) void fc3_kernel(const float* __restrict__ A,
                                                  const float* __restrict__ Wt,
                                                  const float* __restrict__ bias,
                                                  float* __restrict__ C) {
    int gid = blockIdx.x * 256 + threadIdx.x;
    int wid = gid >> 6;
    int lane = gid & 63;
    int m = wid / 10, n = wid - m * 10;
    const float4* a = (const float4*)(A + (size_t)m * 1024);
    const float4* w = (const float4*)(Wt + (size_t)n * 1024);
    float s = 0.f;
#pragma unroll
    for (int it = 0; it < 4; ++it) {
        float4 av = a[it * 64 + lane];
        float4 wv = w[it * 64 + lane];
        s += av.x * wv.x + av.y * wv.y + av.z * wv.z + av.w * wv.w;
    }
#pragma unroll
    for (int off = 32; off; off >>= 1) s += __shfl_xor(s, off);
    if (lane == 0) C[wid] = s + bias[n];
}

// ---------------------------------------------------------------------------
extern "C" void kernel_launch(void* const* d_in, const int* in_sizes, int n_in,
                              void* d_out, int out_size, void* d_ws, size_t ws_size,
                              hipStream_t stream) {
    const float* x   = (const float*)d_in[0];
    const float* bw1 = (const float*)d_in[1];
    const float* sw1 = (const float*)d_in[2];
    const float* sc1 = (const float*)d_in[3];
    const float* bw2 = (const float*)d_in[4];
    const float* sw2 = (const float*)d_in[5];
    const float* sc2 = (const float*)d_in[6];
    const float* bw3 = (const float*)d_in[7];
    const float* sw3 = (const float*)d_in[8];
    const float* sc3 = (const float*)d_in[9];
    const float* bw4 = (const float*)d_in[10];
    const float* sw4 = (const float*)d_in[11];
    const float* sc4 = (const float*)d_in[12];
    const float* w1  = (const float*)d_in[13];
    const float* b1  = (const float*)d_in[14];
    const float* w2  = (const float*)d_in[15];
    const float* b2  = (const float*)d_in[16];
    const float* w3  = (const float*)d_in[17];
    const float* b3  = (const float*)d_in[18];

    float*  wsf = (float*)d_ws;
    ushort* wsu = (ushort*)d_ws;
    float* wp1 = wsf;
    float* wp2 = wsf + 972;
    float* wp3 = wsf + 3564;
    float* wp4 = wsf + 13932;
    ushort* k1h = wsu + 110848;
    ushort* k1l = wsu + 120064;
    ushort* k2h = wsu + 129280;
    ushort* k2l = wsu + 143104;
    ushort* k3h = wsu + 156928;
    ushort* k3l = wsu + 179968;
    ushort* k4h = wsu + 203008;
    ushort* k4l = wsu + 249088;
    ushort* zph = wsu + 295168;
    ushort* zpl = wsu + 295248;
    ushort* A1h = wsu + 524288;
    ushort* A1l = wsu + 4194304;
    ushort* A2h = wsu + 7864320;
    ushort* A2l = wsu + 12582912;
    ushort* A3h = wsu + 524288;
    ushort* A3l = wsu + 3145728;
    ushort* A4h = wsu + 5767168;
    ushort* A4l = wsu + 11010048;
    float* pooled = wsf + 262144;
    float* part1  = wsf + 524288;
    float* fc1o   = wsf + 2621440;
    float* part2  = wsf + 2883584;
    float* fc2o   = wsf + 3932160;

    pack_all<<<(55404 + 255) / 256, 256, 0, stream>>>(bw1, sw1, sc1, bw2, sw2, sc2,
                                                      bw3, sw3, sc3, bw4, sw4, sc4, wsf);
    pack_frags<<<46, 256, 0, stream>>>(wp1, wp2, wp3, wp4, k1h, k1l, k2h, k2l,
                                       k3h, k3l, k4h, k4l, zph, zpl);

    spline_x<<<512, 256, 0, stream>>>(x, A1h, A1l);
    conv_strip<28, 7, 8, 40, 2, 4, 0><<<512, 256, 0, stream>>>(A1h, A1l, k1h, k1l,
                                                               zph, zpl, A2h, A2l);
    conv_strip<36, 9, 12, 56, 3, 8, 1><<<512, 256, 0, stream>>>(A2h, A2l, k2h, k2l,
                                                                zph, zpl, A3h, A3l);
    conv34<1, 16, 0><<<dim3(128, 2), 256, 0, stream>>>(A3h, A3l, k3h, k3l, zph, zpl,
                                                       A4h, A4l, nullptr);
    conv34<2, 32, 1><<<dim3(128, 2), 256, 0, stream>>>(A4h, A4l, k4h, k4l, zph, zpl,
                                                       nullptr, nullptr, pooled);
    fc_big<8><<<dim3(32, 2, 8), 256, 0, stream>>>(pooled, w1, part1, 128, 2048, 2048);
    fc_reduce<8><<<1024, 256, 0, stream>>>(part1, b1, fc1o, 262144, 2048, 1);
    fc_big<8><<<dim3(16, 2, 8), 256, 0, stream>>>(fc1o, w2, part2, 128, 1024, 2048);
    fc_reduce<8><<<512, 256, 0, stream>>>(part2, b2, fc2o, 131072, 1024, 1);
    fc3_kernel<<<320, 256, 0, stream>>>(fc2o, w3, b3, (float*)d_out);
}